// Round 7
// baseline (2165.243 us; speedup 1.0000x reference)
//
#include <hip/hip_runtime.h>
#include <hip/hip_bf16.h>

#define Tn 1024
#define Bn 64
#define En 128
#define G4 512
#define NEGV -10000.0f

typedef _Float16 h8v __attribute__((ext_vector_type(8)));
typedef short bh8 __attribute__((ext_vector_type(8)));
typedef float fl4 __attribute__((ext_vector_type(4)));

// ---------- bf16 helpers ----------
__device__ __forceinline__ float bf2f(unsigned short u) {
    unsigned int v = ((unsigned int)u) << 16;
    float f;
    __builtin_memcpy(&f, &v, 4);
    return f;
}
__device__ __forceinline__ unsigned short f2bf(float f) {
    unsigned int u;
    __builtin_memcpy(&u, &f, 4);
    u = (u + 0x7fffu + ((u >> 16) & 1u)) >> 16;
    return (unsigned short)u;
}

__device__ __forceinline__ float sigf(float x) { return 1.0f / (1.0f + __expf(-x)); }
__device__ __forceinline__ float tanhfast(float x) { return 1.0f - 2.0f / (1.0f + __expf(2.0f * x)); }

// lgkm-only barrier: LDS visibility without draining vmcnt.
// imm 0xC07F = vmcnt(63) expcnt(7) lgkmcnt(0).
__device__ __forceinline__ void barrier_lds_only() {
    __builtin_amdgcn_s_waitcnt(0xC07F);
    __builtin_amdgcn_s_barrier();
}

// =====================================================================
// K1: input projection via bf16 MFMA (unchanged; writes G as [t][b][g] bf16).
// =====================================================================
__global__ __launch_bounds__(256) void k_inproj(
    const int* __restrict__ sent, const float* __restrict__ embed,
    const float* __restrict__ w_ih_f, const float* __restrict__ b_ih_f, const float* __restrict__ b_hh_f,
    const float* __restrict__ w_ih_b, const float* __restrict__ b_ih_b, const float* __restrict__ b_hh_b,
    unsigned short* __restrict__ G_f, unsigned short* __restrict__ G_b)
{
    __shared__ unsigned short Asm[128][136];
    __shared__ unsigned short Bsm[128][136];
    const int tid = threadIdx.x;
    const int dir = blockIdx.z;
    const float* w_ih = dir ? w_ih_b : w_ih_f;
    const float* bi   = dir ? b_ih_b : b_ih_f;
    const float* bh   = dir ? b_hh_b : b_hh_f;
    unsigned short* Gout = dir ? G_b : G_f;

    const int mt = blockIdx.x, nt = blockIdx.y;
    const int r0 = mt * 128, n0 = nt * 128;

    const int srow = tid >> 1;
    const int ch = (tid & 1) * 64;
    {
        const int rg = r0 + srow;
        const int tt = rg >> 6, bb = rg & 63;
        const int tok = sent[bb * Tn + tt];
        const float* ar = embed + (size_t)tok * En + ch;
        const float* br = w_ih + (size_t)(n0 + srow) * En + ch;
#pragma unroll
        for (int i = 0; i < 64; i += 4) {
            float4 v = *(const float4*)(ar + i);
            *(unsigned*)&Asm[srow][ch + i]     = (unsigned)f2bf(v.x) | ((unsigned)f2bf(v.y) << 16);
            *(unsigned*)&Asm[srow][ch + i + 2] = (unsigned)f2bf(v.z) | ((unsigned)f2bf(v.w) << 16);
            float4 u = *(const float4*)(br + i);
            *(unsigned*)&Bsm[srow][ch + i]     = (unsigned)f2bf(u.x) | ((unsigned)f2bf(u.y) << 16);
            *(unsigned*)&Bsm[srow][ch + i + 2] = (unsigned)f2bf(u.z) | ((unsigned)f2bf(u.w) << 16);
        }
    }
    __syncthreads();

    const int w = tid >> 6, lane = tid & 63;
    const int ln = lane & 15, lq = lane >> 4;
    const int nwb = w * 32;

    fl4 acc[8][2];
#pragma unroll
    for (int mi = 0; mi < 8; ++mi)
#pragma unroll
        for (int ni = 0; ni < 2; ++ni) acc[mi][ni] = (fl4){0.f, 0.f, 0.f, 0.f};

#pragma unroll
    for (int kt = 0; kt < 4; ++kt) {
        const int kc = kt * 32 + lq * 8;
        bh8 a[8], bf[2];
#pragma unroll
        for (int mi = 0; mi < 8; ++mi) a[mi] = *(const bh8*)&Asm[mi * 16 + ln][kc];
#pragma unroll
        for (int ni = 0; ni < 2; ++ni) bf[ni] = *(const bh8*)&Bsm[nwb + ni * 16 + ln][kc];
#pragma unroll
        for (int mi = 0; mi < 8; ++mi)
#pragma unroll
            for (int ni = 0; ni < 2; ++ni)
                acc[mi][ni] = __builtin_amdgcn_mfma_f32_16x16x32_bf16(a[mi], bf[ni], acc[mi][ni], 0, 0, 0);
    }

    float bias[2];
#pragma unroll
    for (int ni = 0; ni < 2; ++ni) {
        int n = n0 + nwb + ni * 16 + ln;
        bias[ni] = bi[n] + bh[n];
    }
#pragma unroll
    for (int mi = 0; mi < 8; ++mi)
#pragma unroll
        for (int ni = 0; ni < 2; ++ni) {
            const int n = n0 + nwb + ni * 16 + ln;
#pragma unroll
            for (int rg = 0; rg < 4; ++rg) {
                const int m = mi * 16 + lq * 4 + rg;
                const size_t r = (size_t)(r0 + m);
                Gout[(r << 9) + n] = f2bf(acc[mi][ni][rg] + bias[ni]);
            }
        }
}

// =====================================================================
// K2: LSTM recurrence on the MATRIX pipe, one WG per (batch, dir).
// Grid (64, 2), 512 threads = 8 waves. gates[512] = W[512x128] x h[128]
// via mfma_f32_16x16x32_f16 with the h B-operand BROADCAST across columns:
// every lane's B-frag is h[kt*32+quad*8 ..+8] (ln-independent), so all 16
// columns compute the same (valid) batch -> activations replicate across ln,
// no shuffles/DPP needed, and the single 256B h vector gives conflict-free
// LDS broadcast reads. A = W register-resident (64 VGPRs, loaded once):
// wave w, q: m-tile = gates q*128 + w*16 .. +16.
// C-layout (verified R5/R6): row=quad*4+reg -> lane owns j=w*16+quad*4+reg,
// all 4 gates in acc[q][reg].
// G ([t][b][g] bf16, k_inproj unchanged): 4x8B quad-uniform loads/lane,
// 2-step register pipeline. Only ln==0 writes h (LDS f16 + global bf16).
// lgkm-only barrier: outstanding global ops never drain at the barrier.
// =====================================================================
__global__ __launch_bounds__(512, 2) void k_lstm(
    const float* __restrict__ whh_f, const float* __restrict__ whh_b,
    const unsigned short* __restrict__ G_f, const unsigned short* __restrict__ G_b,
    unsigned short* __restrict__ h_f, unsigned short* __restrict__ h_b)
{
    const int tid = threadIdx.x;
    const int w = tid >> 6;
    const int lane = tid & 63;
    const int ln = lane & 15;
    const int quad = lane >> 4;
    const int b = blockIdx.x;           // batch (one per WG)
    const int dir = blockIdx.y;
    const float* whh = dir ? whh_b : whh_f;
    const unsigned short* Gd = dir ? G_b : G_f;
    unsigned short* ho = dir ? h_b : h_f;

    const int jbase = w * 16 + quad * 4;   // this lane's 4 h-indices (C rows)

    __shared__ __align__(16) unsigned short hls[2][128];   // f16 h, double-buffered

    // ---- weights (A-frags), loaded once: Wf[q][kt], 8 f16 each = 64 VGPRs ----
    h8v Wf[4][4];
#pragma unroll
    for (int q = 0; q < 4; ++q) {
        const float* wrow = whh + (size_t)(q * 128 + w * 16 + ln) * 128;
#pragma unroll
        for (int kt = 0; kt < 4; ++kt) {
            const float* wp = wrow + kt * 32 + quad * 8;
            float4 x = *(const float4*)wp;
            float4 y = *(const float4*)(wp + 4);
            h8v f;
            f[0] = (_Float16)x.x; f[1] = (_Float16)x.y; f[2] = (_Float16)x.z; f[3] = (_Float16)x.w;
            f[4] = (_Float16)y.x; f[5] = (_Float16)y.y; f[6] = (_Float16)y.z; f[7] = (_Float16)y.w;
            Wf[q][kt] = f;
        }
    }

    // zero both h buffers (2*128 f16 = 128 dwords)
    if (tid < 128) ((unsigned*)hls)[tid] = 0u;
    float c[4] = {0.f, 0.f, 0.f, 0.f};
    __syncthreads();

    const int dt = dir ? -1 : 1;
    int t = dir ? (Tn - 1) : 0;

    // ---- G pipeline: ga = step s, gb = step s+1 (uint2 = 4 bf16 of gate q, j jbase..+4)
    uint2 ga[4], gb[4];
    {
        const unsigned short* gp = Gd + (((size_t)t * Bn + b) << 9);
#pragma unroll
        for (int q = 0; q < 4; ++q) ga[q] = *(const uint2*)(gp + q * 128 + jbase);
        const unsigned short* gp2 = Gd + (((size_t)(t + dt) * Bn + b) << 9);
#pragma unroll
        for (int q = 0; q < 4; ++q) gb[q] = *(const uint2*)(gp2 + q * 128 + jbase);
    }

    int p = 0;
    for (int s = 0; s < Tn; ++s) {
        // prefetch G for step s+2 (register pipeline; never drained by barrier)
        uint2 gn[4];
        if (s + 2 < Tn) {
            const unsigned short* gp = Gd + (((size_t)(t + 2 * dt) * Bn + b) << 9);
#pragma unroll
            for (int q = 0; q < 4; ++q) gn[q] = *(const uint2*)(gp + q * 128 + jbase);
        }

        // ---- MFMA: acc[q][r] = dot(W[q*128+w*16+quad*4+r], h)  (all ln identical)
        fl4 acc[4];
#pragma unroll
        for (int q = 0; q < 4; ++q) acc[q] = (fl4){0.f, 0.f, 0.f, 0.f};
#pragma unroll
        for (int kt = 0; kt < 4; ++kt) {
            h8v hfrag = *(const h8v*)&hls[p][kt * 32 + quad * 8];   // broadcast, conflict-free
#pragma unroll
            for (int q = 0; q < 4; ++q)
                acc[q] = __builtin_amdgcn_mfma_f32_16x16x32_f16(Wf[q][kt], hfrag, acc[q], 0, 0, 0);
        }

        // ---- activations (replicated across ln): lane owns j = jbase + r ----
        float hn[4];
#pragma unroll
        for (int r = 0; r < 4; ++r) {
            const unsigned sh = (r & 1) * 16;
            const unsigned d0 = (r < 2) ? ga[0].x : ga[0].y;
            const unsigned d1 = (r < 2) ? ga[1].x : ga[1].y;
            const unsigned d2 = (r < 2) ? ga[2].x : ga[2].y;
            const unsigned d3 = (r < 2) ? ga[3].x : ga[3].y;
            float pi = acc[0][r] + bf2f((unsigned short)(d0 >> sh));
            float pf = acc[1][r] + bf2f((unsigned short)(d1 >> sh));
            float pg = acc[2][r] + bf2f((unsigned short)(d2 >> sh));
            float po = acc[3][r] + bf2f((unsigned short)(d3 >> sh));
            float iv = sigf(pi), fv = sigf(pf), gv = tanhfast(pg), ov = sigf(po);
            c[r] = fv * c[r] + iv * gv;
            hn[r] = ov * tanhfast(c[r]);
        }

        // ---- h writes (one lane per quad-column group): LDS f16 + global bf16 ----
        if (ln == 0) {
            _Float16 q0 = (_Float16)hn[0], q1 = (_Float16)hn[1], q2 = (_Float16)hn[2], q3 = (_Float16)hn[3];
            unsigned short u0, u1, u2, u3;
            __builtin_memcpy(&u0, &q0, 2); __builtin_memcpy(&u1, &q1, 2);
            __builtin_memcpy(&u2, &q2, 2); __builtin_memcpy(&u3, &q3, 2);
            uint2 lv;
            lv.x = (unsigned)u0 | ((unsigned)u1 << 16);
            lv.y = (unsigned)u2 | ((unsigned)u3 << 16);
            *(uint2*)&hls[1 - p][jbase] = lv;

            uint2 gvv;
            gvv.x = (unsigned)f2bf(hn[0]) | ((unsigned)f2bf(hn[1]) << 16);
            gvv.y = (unsigned)f2bf(hn[2]) | ((unsigned)f2bf(hn[3]) << 16);
            *(uint2*)(ho + (((size_t)t * Bn + b) << 7) + jbase) = gvv;
        }

        // rotate G pipeline
#pragma unroll
        for (int q = 0; q < 4; ++q) { ga[q] = gb[q]; gb[q] = gn[q]; }

        barrier_lds_only();
        t += dt;
        p ^= 1;
    }
}

// =====================================================================
// K3: feats (unchanged).
// =====================================================================
__global__ __launch_bounds__(256) void k_feats(
    const unsigned short* __restrict__ h_f, const unsigned short* __restrict__ h_b,
    const float* __restrict__ w_out, const float* __restrict__ b_out,
    float* __restrict__ feats)
{
    __shared__ float wl[256][12];
    __shared__ float bl[12];
    const int tid = threadIdx.x;
#pragma unroll
    for (int s = 0; s < 9; ++s) wl[tid][s] = w_out[s * 256 + tid];
#pragma unroll
    for (int s = 9; s < 12; ++s) wl[tid][s] = 0.0f;
    if (tid < 12) bl[tid] = (tid < 9) ? b_out[tid] : 0.0f;
    __syncthreads();

    const int r = blockIdx.x * 256 + tid;
    const unsigned short* hfr = h_f + (size_t)r * 128;
    const unsigned short* hbr = h_b + (size_t)r * 128;
    float acc[12];
#pragma unroll
    for (int k = 0; k < 12; ++k) acc[k] = bl[k];

    for (int ch = 0; ch < 32; ++ch) {
        const unsigned short* src = (ch < 16) ? (hfr + ch * 8) : (hbr + (ch - 16) * 8);
        uint4 hv = *(const uint4*)src;
        unsigned int hw0 = hv.x, hw1 = hv.y, hw2 = hv.z, hw3 = hv.w;
        const int jb = ch * 8;
#pragma unroll
        for (int q = 0; q < 8; ++q) {
            unsigned int word = (q < 2) ? hw0 : ((q < 4) ? hw1 : ((q < 6) ? hw2 : hw3));
            unsigned short hs = (q & 1) ? (unsigned short)(word >> 16) : (unsigned short)(word & 0xffff);
            float hf = bf2f(hs);
            const float* wrp = &wl[jb + q][0];
            float4 w0 = *(const float4*)(wrp);
            float4 w1 = *(const float4*)(wrp + 4);
            float4 w2 = *(const float4*)(wrp + 8);
            acc[0] += hf * w0.x; acc[1] += hf * w0.y; acc[2] += hf * w0.z; acc[3] += hf * w0.w;
            acc[4] += hf * w1.x; acc[5] += hf * w1.y; acc[6] += hf * w1.z; acc[7] += hf * w1.w;
            acc[8] += hf * w2.x; acc[9] += hf * w2.y; acc[10] += hf * w2.z; acc[11] += hf * w2.w;
        }
    }
    float* fr = feats + (size_t)r * 9;
#pragma unroll
    for (int k = 0; k < 9; ++k) fr[k] = acc[k];
}

// =====================================================================
// K4: Viterbi (unchanged).
// =====================================================================
__global__ __launch_bounds__(64) void k_viterbi(
    const float* __restrict__ feats, const float* __restrict__ trans,
    float* __restrict__ out)
{
    __shared__ __align__(16) unsigned char bp[1024 * 16];
    __shared__ float fl[1024 * 9];
    __shared__ float dl[12];
    __shared__ unsigned char pt[1024];

    const int b = blockIdx.x, tid = threadIdx.x;

    for (int i = tid; i < 9216; i += 64) {
        int t = i / 9;
        int n = i - t * 9;
        fl[i] = feats[((size_t)t * 64 + b) * 9 + n];
    }

    float tr[9];
    float trs = -3.0e38f;
    if (tid < 9) {
#pragma unroll
        for (int p = 0; p < 9; ++p) tr[p] = trans[tid * 9 + p];
        trs = trans[8 * 9 + tid];
    }
    if (tid < 12) dl[tid] = (tid == 7) ? 0.0f : NEGV;
    __syncthreads();

    if (tid < 9) {
        for (int t = 0; t < 1024; ++t) {
            float4 d0 = *(const float4*)&dl[0];
            float4 d1 = *(const float4*)&dl[4];
            float d8 = dl[8];
            float dv0 = d0.x, dv1 = d0.y, dv2 = d0.z, dv3 = d0.w;
            float dv4 = d1.x, dv5 = d1.y, dv6 = d1.z, dv7 = d1.w;
            float m = dv0 + tr[0]; int am = 0;
            float v;
            v = dv1 + tr[1]; if (v > m) { m = v; am = 1; }
            v = dv2 + tr[2]; if (v > m) { m = v; am = 2; }
            v = dv3 + tr[3]; if (v > m) { m = v; am = 3; }
            v = dv4 + tr[4]; if (v > m) { m = v; am = 4; }
            v = dv5 + tr[5]; if (v > m) { m = v; am = 5; }
            v = dv6 + tr[6]; if (v > m) { m = v; am = 6; }
            v = dv7 + tr[7]; if (v > m) { m = v; am = 7; }
            v = d8  + tr[8]; if (v > m) { m = v; am = 8; }
            float nd = m + fl[t * 9 + tid];
            dl[tid] = nd;
            bp[t * 16 + tid] = (unsigned char)am;
        }
    }
    float tv = (tid < 9) ? (dl[tid] + trs) : -3.0e38f;
    int bi = tid;
#pragma unroll
    for (int off = 8; off >= 1; off >>= 1) {
        float ov = __shfl_down(tv, off, 64);
        int oi = __shfl_down(bi, off, 64);
        if (ov > tv || (ov == tv && oi < bi)) { tv = ov; bi = oi; }
    }
    int best = __shfl(bi, 0, 64);
    if (tid == 0) out[b] = tv;

    if (tid == 0) {
        int tag = best;
        for (int t0 = 1023; t0 >= 0; t0 -= 8) {
            uint4 rows[8];
#pragma unroll
            for (int i = 0; i < 8; ++i) rows[i] = *(const uint4*)&bp[(t0 - i) * 16];
#pragma unroll
            for (int i = 0; i < 8; ++i) {
                pt[t0 - i] = (unsigned char)tag;
                uint4 rw = rows[i];
                unsigned int sel = (unsigned int)tag >> 2;
                unsigned int word = (sel == 0) ? rw.x : ((sel == 1) ? rw.y : rw.z);
                tag = (int)((word >> ((tag & 3) * 8)) & 0xffu);
            }
        }
    }
    for (int i = tid; i < 1024; i += 64) {
        out[64 + b * 1024 + i] = (float)pt[i];
    }
}

// =====================================================================
extern "C" void kernel_launch(void* const* d_in, const int* in_sizes, int n_in,
                              void* d_out, int out_size, void* d_ws, size_t ws_size,
                              hipStream_t stream) {
    const int*   sent   = (const int*)d_in[0];
    const float* embed  = (const float*)d_in[1];
    const float* w_ih_f = (const float*)d_in[2];
    const float* w_hh_f = (const float*)d_in[3];
    const float* b_ih_f = (const float*)d_in[4];
    const float* b_hh_f = (const float*)d_in[5];
    const float* w_ih_b = (const float*)d_in[6];
    const float* w_hh_b = (const float*)d_in[7];
    const float* b_ih_b = (const float*)d_in[8];
    const float* b_hh_b = (const float*)d_in[9];
    const float* w_out  = (const float*)d_in[10];
    const float* b_out  = (const float*)d_in[11];
    const float* trans  = (const float*)d_in[12];
    float* out = (float*)d_out;

    unsigned short* G_f = (unsigned short*)d_ws;
    unsigned short* G_b = G_f + (size_t)Tn * Bn * G4;
    unsigned short* h_f = G_b + (size_t)Tn * Bn * G4;
    unsigned short* h_b = h_f + (size_t)Tn * Bn * 128;
    float* feats = (float*)(h_b + (size_t)Tn * Bn * 128);

    k_inproj<<<dim3(512, 4, 2), 256, 0, stream>>>(sent, embed,
        w_ih_f, b_ih_f, b_hh_f, w_ih_b, b_ih_b, b_hh_b, G_f, G_b);
    k_lstm<<<dim3(64, 2), 512, 0, stream>>>(w_hh_f, w_hh_b, G_f, G_b, h_f, h_b);
    k_feats<<<256, 256, 0, stream>>>(h_f, h_b, w_out, b_out, feats);
    k_viterbi<<<64, 64, 0, stream>>>(feats, trans, out);
}

// Round 8
// 2092.879 us; speedup vs baseline: 1.0346x; 1.0346x over previous
//
#include <hip/hip_runtime.h>
#include <hip/hip_bf16.h>

#define Tn 1024
#define Bn 64
#define En 128
#define G4 512
#define NEGV -10000.0f

typedef _Float16 h8v __attribute__((ext_vector_type(8)));
typedef short bh8 __attribute__((ext_vector_type(8)));
typedef float fl4 __attribute__((ext_vector_type(4)));

// ---------- bf16 helpers ----------
__device__ __forceinline__ float bf2f(unsigned short u) {
    unsigned int v = ((unsigned int)u) << 16;
    float f;
    __builtin_memcpy(&f, &v, 4);
    return f;
}
__device__ __forceinline__ unsigned short f2bf(float f) {
    unsigned int u;
    __builtin_memcpy(&u, &f, 4);
    u = (u + 0x7fffu + ((u >> 16) & 1u)) >> 16;
    return (unsigned short)u;
}

__device__ __forceinline__ float sigf(float x) { return 1.0f / (1.0f + __expf(-x)); }
__device__ __forceinline__ float tanhfast(float x) { return 1.0f - 2.0f / (1.0f + __expf(2.0f * x)); }

// lgkm-only barrier: LDS visibility without draining vmcnt.
// imm 0xC07F = vmcnt(63) expcnt(7) lgkmcnt(0).
__device__ __forceinline__ void barrier_lds_only() {
    __builtin_amdgcn_s_waitcnt(0xC07F);
    __builtin_amdgcn_s_barrier();
}

// =====================================================================
// K1: input projection via bf16 MFMA (unchanged; writes G as [t][b][g] bf16).
// =====================================================================
__global__ __launch_bounds__(256) void k_inproj(
    const int* __restrict__ sent, const float* __restrict__ embed,
    const float* __restrict__ w_ih_f, const float* __restrict__ b_ih_f, const float* __restrict__ b_hh_f,
    const float* __restrict__ w_ih_b, const float* __restrict__ b_ih_b, const float* __restrict__ b_hh_b,
    unsigned short* __restrict__ G_f, unsigned short* __restrict__ G_b)
{
    __shared__ unsigned short Asm[128][136];
    __shared__ unsigned short Bsm[128][136];
    const int tid = threadIdx.x;
    const int dir = blockIdx.z;
    const float* w_ih = dir ? w_ih_b : w_ih_f;
    const float* bi   = dir ? b_ih_b : b_ih_f;
    const float* bh   = dir ? b_hh_b : b_hh_f;
    unsigned short* Gout = dir ? G_b : G_f;

    const int mt = blockIdx.x, nt = blockIdx.y;
    const int r0 = mt * 128, n0 = nt * 128;

    const int srow = tid >> 1;
    const int ch = (tid & 1) * 64;
    {
        const int rg = r0 + srow;
        const int tt = rg >> 6, bb = rg & 63;
        const int tok = sent[bb * Tn + tt];
        const float* ar = embed + (size_t)tok * En + ch;
        const float* br = w_ih + (size_t)(n0 + srow) * En + ch;
#pragma unroll
        for (int i = 0; i < 64; i += 4) {
            float4 v = *(const float4*)(ar + i);
            *(unsigned*)&Asm[srow][ch + i]     = (unsigned)f2bf(v.x) | ((unsigned)f2bf(v.y) << 16);
            *(unsigned*)&Asm[srow][ch + i + 2] = (unsigned)f2bf(v.z) | ((unsigned)f2bf(v.w) << 16);
            float4 u = *(const float4*)(br + i);
            *(unsigned*)&Bsm[srow][ch + i]     = (unsigned)f2bf(u.x) | ((unsigned)f2bf(u.y) << 16);
            *(unsigned*)&Bsm[srow][ch + i + 2] = (unsigned)f2bf(u.z) | ((unsigned)f2bf(u.w) << 16);
        }
    }
    __syncthreads();

    const int w = tid >> 6, lane = tid & 63;
    const int ln = lane & 15, lq = lane >> 4;
    const int nwb = w * 32;

    fl4 acc[8][2];
#pragma unroll
    for (int mi = 0; mi < 8; ++mi)
#pragma unroll
        for (int ni = 0; ni < 2; ++ni) acc[mi][ni] = (fl4){0.f, 0.f, 0.f, 0.f};

#pragma unroll
    for (int kt = 0; kt < 4; ++kt) {
        const int kc = kt * 32 + lq * 8;
        bh8 a[8], bf[2];
#pragma unroll
        for (int mi = 0; mi < 8; ++mi) a[mi] = *(const bh8*)&Asm[mi * 16 + ln][kc];
#pragma unroll
        for (int ni = 0; ni < 2; ++ni) bf[ni] = *(const bh8*)&Bsm[nwb + ni * 16 + ln][kc];
#pragma unroll
        for (int mi = 0; mi < 8; ++mi)
#pragma unroll
            for (int ni = 0; ni < 2; ++ni)
                acc[mi][ni] = __builtin_amdgcn_mfma_f32_16x16x32_bf16(a[mi], bf[ni], acc[mi][ni], 0, 0, 0);
    }

    float bias[2];
#pragma unroll
    for (int ni = 0; ni < 2; ++ni) {
        int n = n0 + nwb + ni * 16 + ln;
        bias[ni] = bi[n] + bh[n];
    }
#pragma unroll
    for (int mi = 0; mi < 8; ++mi)
#pragma unroll
        for (int ni = 0; ni < 2; ++ni) {
            const int n = n0 + nwb + ni * 16 + ln;
#pragma unroll
            for (int rg = 0; rg < 4; ++rg) {
                const int m = mi * 16 + lq * 4 + rg;
                const size_t r = (size_t)(r0 + m);
                Gout[(r << 9) + n] = f2bf(acc[mi][ni][rg] + bias[ni]);
            }
        }
}

// =====================================================================
// K2: LSTM recurrence on the MATRIX pipe, one WG per (batch, dir).
// Grid (64, 2), 512 threads = 8 waves. gates[512] = W[512x128] x h[128]
// via mfma_f32_16x16x32_f16 with the h B-operand BROADCAST across columns
// (ln-independent) -> activations replicate across ln, no cross-lane moves.
// A = W register-resident (64 VGPRs, loaded once).
// C-layout (verified R5-R7): lane owns j=w*16+quad*4+r, all 4 gates in acc[q][r].
//
// G pipeline (THE R7 FIX): step loop unrolled x4 with a 4-slot STATIC register
// pipeline gp[4][4] (slot = s mod 4, prefetch distance 4). No rotation copies
// -> the value consumed at step s was loaded at s-4 (~2500+ cyc slack >> 900
// cyc HBM latency), so the compiler's vmcnt wait finds it already complete.
// R7's 2-step rotating pipeline forced a same-iteration vmcnt drain = ~1700
// cyc/step of exposed HBM latency; this removes it.
// lgkm-only barrier: outstanding global ops never drain at the barrier.
// =====================================================================
__global__ __launch_bounds__(512, 2) void k_lstm(
    const float* __restrict__ whh_f, const float* __restrict__ whh_b,
    const unsigned short* __restrict__ G_f, const unsigned short* __restrict__ G_b,
    unsigned short* __restrict__ h_f, unsigned short* __restrict__ h_b)
{
    const int tid = threadIdx.x;
    const int w = tid >> 6;
    const int lane = tid & 63;
    const int ln = lane & 15;
    const int quad = lane >> 4;
    const int b = blockIdx.x;           // batch (one per WG)
    const int dir = blockIdx.y;
    const float* whh = dir ? whh_b : whh_f;
    const unsigned short* Gd = dir ? G_b : G_f;
    unsigned short* ho = dir ? h_b : h_f;

    const int jbase = w * 16 + quad * 4;   // this lane's 4 h-indices (C rows)

    __shared__ __align__(16) unsigned short hls[2][128];   // f16 h, double-buffered

    // ---- weights (A-frags), loaded once: Wf[q][kt], 8 f16 each = 64 VGPRs ----
    h8v Wf[4][4];
#pragma unroll
    for (int q = 0; q < 4; ++q) {
        const float* wrow = whh + (size_t)(q * 128 + w * 16 + ln) * 128;
#pragma unroll
        for (int kt = 0; kt < 4; ++kt) {
            const float* wp = wrow + kt * 32 + quad * 8;
            float4 x = *(const float4*)wp;
            float4 y = *(const float4*)(wp + 4);
            h8v f;
            f[0] = (_Float16)x.x; f[1] = (_Float16)x.y; f[2] = (_Float16)x.z; f[3] = (_Float16)x.w;
            f[4] = (_Float16)y.x; f[5] = (_Float16)y.y; f[6] = (_Float16)y.z; f[7] = (_Float16)y.w;
            Wf[q][kt] = f;
        }
    }

    // zero both h buffers (2*128 f16 = 128 dwords)
    if (tid < 128) ((unsigned*)hls)[tid] = 0u;
    float c[4] = {0.f, 0.f, 0.f, 0.f};
    __syncthreads();

    // ---- G pipeline preload: slots 0..3 hold steps 0..3 ----
    uint2 gp[4][4];
#pragma unroll
    for (int u = 0; u < 4; ++u) {
        const int tt = dir ? (Tn - 1 - u) : u;
        const unsigned short* gpp = Gd + (((size_t)tt * Bn + b) << 9);
#pragma unroll
        for (int q = 0; q < 4; ++q) gp[u][q] = *(const uint2*)(gpp + q * 128 + jbase);
    }

    for (int blk = 0; blk < Tn / 4; ++blk) {
#pragma unroll
        for (int u = 0; u < 4; ++u) {
            const int s = blk * 4 + u;
            const int t = dir ? (Tn - 1 - s) : s;
            const int p = u & 1;          // h buffer parity (blk*4 is even)

            // consume slot u (loaded at step s-4; vmcnt wait finds it done)
            uint2 ga[4];
#pragma unroll
            for (int q = 0; q < 4; ++q) ga[q] = gp[u][q];

            // prefetch step s+4 into slot u (static index -> no copies)
            if (s + 4 < Tn) {
                const int tt = dir ? (Tn - 1 - (s + 4)) : (s + 4);
                const unsigned short* gpp = Gd + (((size_t)tt * Bn + b) << 9);
#pragma unroll
                for (int q = 0; q < 4; ++q) gp[u][q] = *(const uint2*)(gpp + q * 128 + jbase);
            }

            // ---- MFMA: acc[q][r] = dot(W[q*128+jbase+r], h)  (all ln identical)
            fl4 acc[4];
#pragma unroll
            for (int q = 0; q < 4; ++q) acc[q] = (fl4){0.f, 0.f, 0.f, 0.f};
#pragma unroll
            for (int kt = 0; kt < 4; ++kt) {
                h8v hfrag = *(const h8v*)&hls[p][kt * 32 + quad * 8];   // broadcast, conflict-free
#pragma unroll
                for (int q = 0; q < 4; ++q)
                    acc[q] = __builtin_amdgcn_mfma_f32_16x16x32_f16(Wf[q][kt], hfrag, acc[q], 0, 0, 0);
            }

            // ---- activations (replicated across ln): lane owns j = jbase + r ----
            float hn[4];
#pragma unroll
            for (int r = 0; r < 4; ++r) {
                const unsigned sh = (r & 1) * 16;
                const unsigned d0 = (r < 2) ? ga[0].x : ga[0].y;
                const unsigned d1 = (r < 2) ? ga[1].x : ga[1].y;
                const unsigned d2 = (r < 2) ? ga[2].x : ga[2].y;
                const unsigned d3 = (r < 2) ? ga[3].x : ga[3].y;
                float pi = acc[0][r] + bf2f((unsigned short)(d0 >> sh));
                float pf = acc[1][r] + bf2f((unsigned short)(d1 >> sh));
                float pg = acc[2][r] + bf2f((unsigned short)(d2 >> sh));
                float po = acc[3][r] + bf2f((unsigned short)(d3 >> sh));
                float iv = sigf(pi), fv = sigf(pf), gv = tanhfast(pg), ov = sigf(po);
                c[r] = fv * c[r] + iv * gv;
                hn[r] = ov * tanhfast(c[r]);
            }

            // ---- h writes (ln==0 lanes): LDS f16 + global bf16 ----
            if (ln == 0) {
                _Float16 q0 = (_Float16)hn[0], q1 = (_Float16)hn[1], q2 = (_Float16)hn[2], q3 = (_Float16)hn[3];
                unsigned short u0, u1, u2, u3;
                __builtin_memcpy(&u0, &q0, 2); __builtin_memcpy(&u1, &q1, 2);
                __builtin_memcpy(&u2, &q2, 2); __builtin_memcpy(&u3, &q3, 2);
                uint2 lv;
                lv.x = (unsigned)u0 | ((unsigned)u1 << 16);
                lv.y = (unsigned)u2 | ((unsigned)u3 << 16);
                *(uint2*)&hls[1 - p][jbase] = lv;

                uint2 gvv;
                gvv.x = (unsigned)f2bf(hn[0]) | ((unsigned)f2bf(hn[1]) << 16);
                gvv.y = (unsigned)f2bf(hn[2]) | ((unsigned)f2bf(hn[3]) << 16);
                *(uint2*)(ho + (((size_t)t * Bn + b) << 7) + jbase) = gvv;
            }

            barrier_lds_only();
        }
    }
}

// =====================================================================
// K3: feats (unchanged).
// =====================================================================
__global__ __launch_bounds__(256) void k_feats(
    const unsigned short* __restrict__ h_f, const unsigned short* __restrict__ h_b,
    const float* __restrict__ w_out, const float* __restrict__ b_out,
    float* __restrict__ feats)
{
    __shared__ float wl[256][12];
    __shared__ float bl[12];
    const int tid = threadIdx.x;
#pragma unroll
    for (int s = 0; s < 9; ++s) wl[tid][s] = w_out[s * 256 + tid];
#pragma unroll
    for (int s = 9; s < 12; ++s) wl[tid][s] = 0.0f;
    if (tid < 12) bl[tid] = (tid < 9) ? b_out[tid] : 0.0f;
    __syncthreads();

    const int r = blockIdx.x * 256 + tid;
    const unsigned short* hfr = h_f + (size_t)r * 128;
    const unsigned short* hbr = h_b + (size_t)r * 128;
    float acc[12];
#pragma unroll
    for (int k = 0; k < 12; ++k) acc[k] = bl[k];

    for (int ch = 0; ch < 32; ++ch) {
        const unsigned short* src = (ch < 16) ? (hfr + ch * 8) : (hbr + (ch - 16) * 8);
        uint4 hv = *(const uint4*)src;
        unsigned int hw0 = hv.x, hw1 = hv.y, hw2 = hv.z, hw3 = hv.w;
        const int jb = ch * 8;
#pragma unroll
        for (int q = 0; q < 8; ++q) {
            unsigned int word = (q < 2) ? hw0 : ((q < 4) ? hw1 : ((q < 6) ? hw2 : hw3));
            unsigned short hs = (q & 1) ? (unsigned short)(word >> 16) : (unsigned short)(word & 0xffff);
            float hf = bf2f(hs);
            const float* wrp = &wl[jb + q][0];
            float4 w0 = *(const float4*)(wrp);
            float4 w1 = *(const float4*)(wrp + 4);
            float4 w2 = *(const float4*)(wrp + 8);
            acc[0] += hf * w0.x; acc[1] += hf * w0.y; acc[2] += hf * w0.z; acc[3] += hf * w0.w;
            acc[4] += hf * w1.x; acc[5] += hf * w1.y; acc[6] += hf * w1.z; acc[7] += hf * w1.w;
            acc[8] += hf * w2.x; acc[9] += hf * w2.y; acc[10] += hf * w2.z; acc[11] += hf * w2.w;
        }
    }
    float* fr = feats + (size_t)r * 9;
#pragma unroll
    for (int k = 0; k < 9; ++k) fr[k] = acc[k];
}

// =====================================================================
// K4: Viterbi (unchanged).
// =====================================================================
__global__ __launch_bounds__(64) void k_viterbi(
    const float* __restrict__ feats, const float* __restrict__ trans,
    float* __restrict__ out)
{
    __shared__ __align__(16) unsigned char bp[1024 * 16];
    __shared__ float fl[1024 * 9];
    __shared__ float dl[12];
    __shared__ unsigned char pt[1024];

    const int b = blockIdx.x, tid = threadIdx.x;

    for (int i = tid; i < 9216; i += 64) {
        int t = i / 9;
        int n = i - t * 9;
        fl[i] = feats[((size_t)t * 64 + b) * 9 + n];
    }

    float tr[9];
    float trs = -3.0e38f;
    if (tid < 9) {
#pragma unroll
        for (int p = 0; p < 9; ++p) tr[p] = trans[tid * 9 + p];
        trs = trans[8 * 9 + tid];
    }
    if (tid < 12) dl[tid] = (tid == 7) ? 0.0f : NEGV;
    __syncthreads();

    if (tid < 9) {
        for (int t = 0; t < 1024; ++t) {
            float4 d0 = *(const float4*)&dl[0];
            float4 d1 = *(const float4*)&dl[4];
            float d8 = dl[8];
            float dv0 = d0.x, dv1 = d0.y, dv2 = d0.z, dv3 = d0.w;
            float dv4 = d1.x, dv5 = d1.y, dv6 = d1.z, dv7 = d1.w;
            float m = dv0 + tr[0]; int am = 0;
            float v;
            v = dv1 + tr[1]; if (v > m) { m = v; am = 1; }
            v = dv2 + tr[2]; if (v > m) { m = v; am = 2; }
            v = dv3 + tr[3]; if (v > m) { m = v; am = 3; }
            v = dv4 + tr[4]; if (v > m) { m = v; am = 4; }
            v = dv5 + tr[5]; if (v > m) { m = v; am = 5; }
            v = dv6 + tr[6]; if (v > m) { m = v; am = 6; }
            v = dv7 + tr[7]; if (v > m) { m = v; am = 7; }
            v = d8  + tr[8]; if (v > m) { m = v; am = 8; }
            float nd = m + fl[t * 9 + tid];
            dl[tid] = nd;
            bp[t * 16 + tid] = (unsigned char)am;
        }
    }
    float tv = (tid < 9) ? (dl[tid] + trs) : -3.0e38f;
    int bi = tid;
#pragma unroll
    for (int off = 8; off >= 1; off >>= 1) {
        float ov = __shfl_down(tv, off, 64);
        int oi = __shfl_down(bi, off, 64);
        if (ov > tv || (ov == tv && oi < bi)) { tv = ov; bi = oi; }
    }
    int best = __shfl(bi, 0, 64);
    if (tid == 0) out[b] = tv;

    if (tid == 0) {
        int tag = best;
        for (int t0 = 1023; t0 >= 0; t0 -= 8) {
            uint4 rows[8];
#pragma unroll
            for (int i = 0; i < 8; ++i) rows[i] = *(const uint4*)&bp[(t0 - i) * 16];
#pragma unroll
            for (int i = 0; i < 8; ++i) {
                pt[t0 - i] = (unsigned char)tag;
                uint4 rw = rows[i];
                unsigned int sel = (unsigned int)tag >> 2;
                unsigned int word = (sel == 0) ? rw.x : ((sel == 1) ? rw.y : rw.z);
                tag = (int)((word >> ((tag & 3) * 8)) & 0xffu);
            }
        }
    }
    for (int i = tid; i < 1024; i += 64) {
        out[64 + b * 1024 + i] = (float)pt[i];
    }
}

// =====================================================================
extern "C" void kernel_launch(void* const* d_in, const int* in_sizes, int n_in,
                              void* d_out, int out_size, void* d_ws, size_t ws_size,
                              hipStream_t stream) {
    const int*   sent   = (const int*)d_in[0];
    const float* embed  = (const float*)d_in[1];
    const float* w_ih_f = (const float*)d_in[2];
    const float* w_hh_f = (const float*)d_in[3];
    const float* b_ih_f = (const float*)d_in[4];
    const float* b_hh_f = (const float*)d_in[5];
    const float* w_ih_b = (const float*)d_in[6];
    const float* w_hh_b = (const float*)d_in[7];
    const float* b_ih_b = (const float*)d_in[8];
    const float* b_hh_b = (const float*)d_in[9];
    const float* w_out  = (const float*)d_in[10];
    const float* b_out  = (const float*)d_in[11];
    const float* trans  = (const float*)d_in[12];
    float* out = (float*)d_out;

    unsigned short* G_f = (unsigned short*)d_ws;
    unsigned short* G_b = G_f + (size_t)Tn * Bn * G4;
    unsigned short* h_f = G_b + (size_t)Tn * Bn * G4;
    unsigned short* h_b = h_f + (size_t)Tn * Bn * 128;
    float* feats = (float*)(h_b + (size_t)Tn * Bn * 128);

    k_inproj<<<dim3(512, 4, 2), 256, 0, stream>>>(sent, embed,
        w_ih_f, b_ih_f, b_hh_f, w_ih_b, b_ih_b, b_hh_b, G_f, G_b);
    k_lstm<<<dim3(64, 2), 512, 0, stream>>>(w_hh_f, w_hh_b, G_f, G_b, h_f, h_b);
    k_feats<<<256, 256, 0, stream>>>(h_f, h_b, w_out, b_out, feats);
    k_viterbi<<<64, 64, 0, stream>>>(feats, trans, out);
}

// Round 9
// 1048.349 us; speedup vs baseline: 2.0654x; 1.9964x over previous
//
#include <hip/hip_runtime.h>
#include <hip/hip_bf16.h>

#define Tn 1024
#define Bn 64
#define En 128
#define G4 512
#define NEGV -10000.0f

typedef _Float16 h8v __attribute__((ext_vector_type(8)));
typedef short bh8 __attribute__((ext_vector_type(8)));
typedef float fl4 __attribute__((ext_vector_type(4)));

// ---------- bf16 helpers ----------
__device__ __forceinline__ float bf2f(unsigned short u) {
    unsigned int v = ((unsigned int)u) << 16;
    float f;
    __builtin_memcpy(&f, &v, 4);
    return f;
}
__device__ __forceinline__ unsigned short f2bf(float f) {
    unsigned int u;
    __builtin_memcpy(&u, &f, 4);
    u = (u + 0x7fffu + ((u >> 16) & 1u)) >> 16;
    return (unsigned short)u;
}

__device__ __forceinline__ float sigf(float x) { return 1.0f / (1.0f + __expf(-x)); }
__device__ __forceinline__ float tanhfast(float x) { return 1.0f - 2.0f / (1.0f + __expf(2.0f * x)); }

// lgkm-only barrier: LDS visibility without draining vmcnt.
// imm 0xC07F = vmcnt(63) expcnt(7) lgkmcnt(0).
__device__ __forceinline__ void barrier_lds_only() {
    __builtin_amdgcn_s_waitcnt(0xC07F);
    __builtin_amdgcn_s_barrier();
}

// =====================================================================
// K1: input projection via bf16 MFMA (unchanged; writes G as [t][b][g] bf16).
// =====================================================================
__global__ __launch_bounds__(256) void k_inproj(
    const int* __restrict__ sent, const float* __restrict__ embed,
    const float* __restrict__ w_ih_f, const float* __restrict__ b_ih_f, const float* __restrict__ b_hh_f,
    const float* __restrict__ w_ih_b, const float* __restrict__ b_ih_b, const float* __restrict__ b_hh_b,
    unsigned short* __restrict__ G_f, unsigned short* __restrict__ G_b)
{
    __shared__ unsigned short Asm[128][136];
    __shared__ unsigned short Bsm[128][136];
    const int tid = threadIdx.x;
    const int dir = blockIdx.z;
    const float* w_ih = dir ? w_ih_b : w_ih_f;
    const float* bi   = dir ? b_ih_b : b_ih_f;
    const float* bh   = dir ? b_hh_b : b_hh_f;
    unsigned short* Gout = dir ? G_b : G_f;

    const int mt = blockIdx.x, nt = blockIdx.y;
    const int r0 = mt * 128, n0 = nt * 128;

    const int srow = tid >> 1;
    const int ch = (tid & 1) * 64;
    {
        const int rg = r0 + srow;
        const int tt = rg >> 6, bb = rg & 63;
        const int tok = sent[bb * Tn + tt];
        const float* ar = embed + (size_t)tok * En + ch;
        const float* br = w_ih + (size_t)(n0 + srow) * En + ch;
#pragma unroll
        for (int i = 0; i < 64; i += 4) {
            float4 v = *(const float4*)(ar + i);
            *(unsigned*)&Asm[srow][ch + i]     = (unsigned)f2bf(v.x) | ((unsigned)f2bf(v.y) << 16);
            *(unsigned*)&Asm[srow][ch + i + 2] = (unsigned)f2bf(v.z) | ((unsigned)f2bf(v.w) << 16);
            float4 u = *(const float4*)(br + i);
            *(unsigned*)&Bsm[srow][ch + i]     = (unsigned)f2bf(u.x) | ((unsigned)f2bf(u.y) << 16);
            *(unsigned*)&Bsm[srow][ch + i + 2] = (unsigned)f2bf(u.z) | ((unsigned)f2bf(u.w) << 16);
        }
    }
    __syncthreads();

    const int w = tid >> 6, lane = tid & 63;
    const int ln = lane & 15, lq = lane >> 4;
    const int nwb = w * 32;

    fl4 acc[8][2];
#pragma unroll
    for (int mi = 0; mi < 8; ++mi)
#pragma unroll
        for (int ni = 0; ni < 2; ++ni) acc[mi][ni] = (fl4){0.f, 0.f, 0.f, 0.f};

#pragma unroll
    for (int kt = 0; kt < 4; ++kt) {
        const int kc = kt * 32 + lq * 8;
        bh8 a[8], bf[2];
#pragma unroll
        for (int mi = 0; mi < 8; ++mi) a[mi] = *(const bh8*)&Asm[mi * 16 + ln][kc];
#pragma unroll
        for (int ni = 0; ni < 2; ++ni) bf[ni] = *(const bh8*)&Bsm[nwb + ni * 16 + ln][kc];
#pragma unroll
        for (int mi = 0; mi < 8; ++mi)
#pragma unroll
            for (int ni = 0; ni < 2; ++ni)
                acc[mi][ni] = __builtin_amdgcn_mfma_f32_16x16x32_bf16(a[mi], bf[ni], acc[mi][ni], 0, 0, 0);
    }

    float bias[2];
#pragma unroll
    for (int ni = 0; ni < 2; ++ni) {
        int n = n0 + nwb + ni * 16 + ln;
        bias[ni] = bi[n] + bh[n];
    }
#pragma unroll
    for (int mi = 0; mi < 8; ++mi)
#pragma unroll
        for (int ni = 0; ni < 2; ++ni) {
            const int n = n0 + nwb + ni * 16 + ln;
#pragma unroll
            for (int rg = 0; rg < 4; ++rg) {
                const int m = mi * 16 + lq * 4 + rg;
                const size_t r = (size_t)(r0 + m);
                Gout[(r << 9) + n] = f2bf(acc[mi][ni][rg] + bias[ni]);
            }
        }
}

// =====================================================================
// K2: LSTM recurrence on the MATRIX pipe, one WG per (batch, dir).
// Grid (64, 2), 512 threads = 8 waves.
//
// OPERAND-SWAPPED MFMA (the R8 fix): A = h broadcast (rows replicated),
// B = W (gate = COLUMN). D[m][n] = dot(h, W[gate n]) independent of m, so
// lane (w, ln) holds ALL FOUR gate dots of the single h-index j = w*16+ln
// in acc[q][0] (replicated across quads only). Activations are computed
// ONCE per h-element per quad: ~65 VALU instrs/wave/step vs R8's ~209
// (R8 replicated activations across 16 ln columns -> VALU-issue-bound).
// Both fragment layouts HW-verified this session: A-row=lane&15 (R6-R8,
// W-as-A passed), B-col=lane&15 (R6, batch-as-B passed).
//
// G: 4 scalar ushort loads/lane (32B coalesced per (w,q) group), 4-slot
// static register pipeline (prefetch distance 4). quad==0 lanes write h
// (2B LDS f16 + 2B global bf16, 32B coalesced per wave).
// lgkm-only barrier: outstanding global ops never drain at the barrier.
// =====================================================================
__global__ __launch_bounds__(512, 2) void k_lstm(
    const float* __restrict__ whh_f, const float* __restrict__ whh_b,
    const unsigned short* __restrict__ G_f, const unsigned short* __restrict__ G_b,
    unsigned short* __restrict__ h_f, unsigned short* __restrict__ h_b)
{
    const int tid = threadIdx.x;
    const int w = tid >> 6;
    const int lane = tid & 63;
    const int ln = lane & 15;
    const int quad = lane >> 4;
    const int b = blockIdx.x;           // batch (one per WG)
    const int dir = blockIdx.y;
    const float* whh = dir ? whh_b : whh_f;
    const unsigned short* Gd = dir ? G_b : G_f;
    unsigned short* ho = dir ? h_b : h_f;

    const int j = w * 16 + ln;          // this lane's h index (gate column)

    __shared__ __align__(16) unsigned short hls[2][128];   // f16 h, double-buffered

    // ---- weights (B-frags): Wf[q][kt] = W[q*128 + j][kt*32 + quad*8 .. +8]
    // (identical load code to R8; only the MFMA operand ROLE changes)
    h8v Wf[4][4];
#pragma unroll
    for (int q = 0; q < 4; ++q) {
        const float* wrow = whh + (size_t)(q * 128 + j) * 128;
#pragma unroll
        for (int kt = 0; kt < 4; ++kt) {
            const float* wp = wrow + kt * 32 + quad * 8;
            float4 x = *(const float4*)wp;
            float4 y = *(const float4*)(wp + 4);
            h8v f;
            f[0] = (_Float16)x.x; f[1] = (_Float16)x.y; f[2] = (_Float16)x.z; f[3] = (_Float16)x.w;
            f[4] = (_Float16)y.x; f[5] = (_Float16)y.y; f[6] = (_Float16)y.z; f[7] = (_Float16)y.w;
            Wf[q][kt] = f;
        }
    }

    // zero both h buffers (2*128 f16 = 128 dwords)
    if (tid < 128) ((unsigned*)hls)[tid] = 0u;
    float c = 0.0f;
    __syncthreads();

    // ---- G pipeline preload: slot u holds the 4 gate pre-acts of step u ----
    unsigned short gp[4][4];
#pragma unroll
    for (int u = 0; u < 4; ++u) {
        const int tt = dir ? (Tn - 1 - u) : u;
        const unsigned short* gpp = Gd + (((size_t)tt * Bn + b) << 9) + j;
#pragma unroll
        for (int q = 0; q < 4; ++q) gp[u][q] = gpp[q * 128];
    }

    for (int blk = 0; blk < Tn / 4; ++blk) {
#pragma unroll
        for (int u = 0; u < 4; ++u) {
            const int s = blk * 4 + u;
            const int t = dir ? (Tn - 1 - s) : s;
            const int p = u & 1;          // h buffer parity (blk*4 is even)

            // consume slot u (loaded at step s-4; vmcnt wait finds it done)
            const unsigned short ga0 = gp[u][0], ga1 = gp[u][1];
            const unsigned short ga2 = gp[u][2], ga3 = gp[u][3];

            // prefetch step s+4 into slot u (static index -> no copies)
            if (s + 4 < Tn) {
                const int tt = dir ? (Tn - 1 - (s + 4)) : (s + 4);
                const unsigned short* gpp = Gd + (((size_t)tt * Bn + b) << 9) + j;
#pragma unroll
                for (int q = 0; q < 4; ++q) gp[u][q] = gpp[q * 128];
            }

            // ---- MFMA (operands swapped): acc[q][*] = dot(h, W[q*128 + j])
            fl4 acc[4];
#pragma unroll
            for (int q = 0; q < 4; ++q) acc[q] = (fl4){0.f, 0.f, 0.f, 0.f};
#pragma unroll
            for (int kt = 0; kt < 4; ++kt) {
                h8v hfrag = *(const h8v*)&hls[p][kt * 32 + quad * 8];   // broadcast read
#pragma unroll
                for (int q = 0; q < 4; ++q)
                    acc[q] = __builtin_amdgcn_mfma_f32_16x16x32_f16(hfrag, Wf[q][kt], acc[q], 0, 0, 0);
            }

            // ---- activation: ONE h-element per lane (replicated across quads) ----
            float pi = acc[0][0] + bf2f(ga0);
            float pf = acc[1][0] + bf2f(ga1);
            float pg = acc[2][0] + bf2f(ga2);
            float po = acc[3][0] + bf2f(ga3);
            float iv = sigf(pi), fv = sigf(pf), gv = tanhfast(pg), ov = sigf(po);
            c = fv * c + iv * gv;
            float hn = ov * tanhfast(c);

            // ---- h writes (quad==0 lanes: 128 lanes cover all j): LDS f16 + global bf16
            if (quad == 0) {
                _Float16 hf16 = (_Float16)hn;
                unsigned short hu;
                __builtin_memcpy(&hu, &hf16, 2);
                hls[1 - p][j] = hu;
                ho[(((size_t)t * Bn + b) << 7) + j] = f2bf(hn);
            }

            barrier_lds_only();
        }
    }
}

// =====================================================================
// K3: feats (unchanged).
// =====================================================================
__global__ __launch_bounds__(256) void k_feats(
    const unsigned short* __restrict__ h_f, const unsigned short* __restrict__ h_b,
    const float* __restrict__ w_out, const float* __restrict__ b_out,
    float* __restrict__ feats)
{
    __shared__ float wl[256][12];
    __shared__ float bl[12];
    const int tid = threadIdx.x;
#pragma unroll
    for (int s = 0; s < 9; ++s) wl[tid][s] = w_out[s * 256 + tid];
#pragma unroll
    for (int s = 9; s < 12; ++s) wl[tid][s] = 0.0f;
    if (tid < 12) bl[tid] = (tid < 9) ? b_out[tid] : 0.0f;
    __syncthreads();

    const int r = blockIdx.x * 256 + tid;
    const unsigned short* hfr = h_f + (size_t)r * 128;
    const unsigned short* hbr = h_b + (size_t)r * 128;
    float acc[12];
#pragma unroll
    for (int k = 0; k < 12; ++k) acc[k] = bl[k];

    for (int ch = 0; ch < 32; ++ch) {
        const unsigned short* src = (ch < 16) ? (hfr + ch * 8) : (hbr + (ch - 16) * 8);
        uint4 hv = *(const uint4*)src;
        unsigned int hw0 = hv.x, hw1 = hv.y, hw2 = hv.z, hw3 = hv.w;
        const int jb = ch * 8;
#pragma unroll
        for (int q = 0; q < 8; ++q) {
            unsigned int word = (q < 2) ? hw0 : ((q < 4) ? hw1 : ((q < 6) ? hw2 : hw3));
            unsigned short hs = (q & 1) ? (unsigned short)(word >> 16) : (unsigned short)(word & 0xffff);
            float hf = bf2f(hs);
            const float* wrp = &wl[jb + q][0];
            float4 w0 = *(const float4*)(wrp);
            float4 w1 = *(const float4*)(wrp + 4);
            float4 w2 = *(const float4*)(wrp + 8);
            acc[0] += hf * w0.x; acc[1] += hf * w0.y; acc[2] += hf * w0.z; acc[3] += hf * w0.w;
            acc[4] += hf * w1.x; acc[5] += hf * w1.y; acc[6] += hf * w1.z; acc[7] += hf * w1.w;
            acc[8] += hf * w2.x; acc[9] += hf * w2.y; acc[10] += hf * w2.z; acc[11] += hf * w2.w;
        }
    }
    float* fr = feats + (size_t)r * 9;
#pragma unroll
    for (int k = 0; k < 9; ++k) fr[k] = acc[k];
}

// =====================================================================
// K4: Viterbi (unchanged).
// =====================================================================
__global__ __launch_bounds__(64) void k_viterbi(
    const float* __restrict__ feats, const float* __restrict__ trans,
    float* __restrict__ out)
{
    __shared__ __align__(16) unsigned char bp[1024 * 16];
    __shared__ float fl[1024 * 9];
    __shared__ float dl[12];
    __shared__ unsigned char pt[1024];

    const int b = blockIdx.x, tid = threadIdx.x;

    for (int i = tid; i < 9216; i += 64) {
        int t = i / 9;
        int n = i - t * 9;
        fl[i] = feats[((size_t)t * 64 + b) * 9 + n];
    }

    float tr[9];
    float trs = -3.0e38f;
    if (tid < 9) {
#pragma unroll
        for (int p = 0; p < 9; ++p) tr[p] = trans[tid * 9 + p];
        trs = trans[8 * 9 + tid];
    }
    if (tid < 12) dl[tid] = (tid == 7) ? 0.0f : NEGV;
    __syncthreads();

    if (tid < 9) {
        for (int t = 0; t < 1024; ++t) {
            float4 d0 = *(const float4*)&dl[0];
            float4 d1 = *(const float4*)&dl[4];
            float d8 = dl[8];
            float dv0 = d0.x, dv1 = d0.y, dv2 = d0.z, dv3 = d0.w;
            float dv4 = d1.x, dv5 = d1.y, dv6 = d1.z, dv7 = d1.w;
            float m = dv0 + tr[0]; int am = 0;
            float v;
            v = dv1 + tr[1]; if (v > m) { m = v; am = 1; }
            v = dv2 + tr[2]; if (v > m) { m = v; am = 2; }
            v = dv3 + tr[3]; if (v > m) { m = v; am = 3; }
            v = dv4 + tr[4]; if (v > m) { m = v; am = 4; }
            v = dv5 + tr[5]; if (v > m) { m = v; am = 5; }
            v = dv6 + tr[6]; if (v > m) { m = v; am = 6; }
            v = dv7 + tr[7]; if (v > m) { m = v; am = 7; }
            v = d8  + tr[8]; if (v > m) { m = v; am = 8; }
            float nd = m + fl[t * 9 + tid];
            dl[tid] = nd;
            bp[t * 16 + tid] = (unsigned char)am;
        }
    }
    float tv = (tid < 9) ? (dl[tid] + trs) : -3.0e38f;
    int bi = tid;
#pragma unroll
    for (int off = 8; off >= 1; off >>= 1) {
        float ov = __shfl_down(tv, off, 64);
        int oi = __shfl_down(bi, off, 64);
        if (ov > tv || (ov == tv && oi < bi)) { tv = ov; bi = oi; }
    }
    int best = __shfl(bi, 0, 64);
    if (tid == 0) out[b] = tv;

    if (tid == 0) {
        int tag = best;
        for (int t0 = 1023; t0 >= 0; t0 -= 8) {
            uint4 rows[8];
#pragma unroll
            for (int i = 0; i < 8; ++i) rows[i] = *(const uint4*)&bp[(t0 - i) * 16];
#pragma unroll
            for (int i = 0; i < 8; ++i) {
                pt[t0 - i] = (unsigned char)tag;
                uint4 rw = rows[i];
                unsigned int sel = (unsigned int)tag >> 2;
                unsigned int word = (sel == 0) ? rw.x : ((sel == 1) ? rw.y : rw.z);
                tag = (int)((word >> ((tag & 3) * 8)) & 0xffu);
            }
        }
    }
    for (int i = tid; i < 1024; i += 64) {
        out[64 + b * 1024 + i] = (float)pt[i];
    }
}

// =====================================================================
extern "C" void kernel_launch(void* const* d_in, const int* in_sizes, int n_in,
                              void* d_out, int out_size, void* d_ws, size_t ws_size,
                              hipStream_t stream) {
    const int*   sent   = (const int*)d_in[0];
    const float* embed  = (const float*)d_in[1];
    const float* w_ih_f = (const float*)d_in[2];
    const float* w_hh_f = (const float*)d_in[3];
    const float* b_ih_f = (const float*)d_in[4];
    const float* b_hh_f = (const float*)d_in[5];
    const float* w_ih_b = (const float*)d_in[6];
    const float* w_hh_b = (const float*)d_in[7];
    const float* b_ih_b = (const float*)d_in[8];
    const float* b_hh_b = (const float*)d_in[9];
    const float* w_out  = (const float*)d_in[10];
    const float* b_out  = (const float*)d_in[11];
    const float* trans  = (const float*)d_in[12];
    float* out = (float*)d_out;

    unsigned short* G_f = (unsigned short*)d_ws;
    unsigned short* G_b = G_f + (size_t)Tn * Bn * G4;
    unsigned short* h_f = G_b + (size_t)Tn * Bn * G4;
    unsigned short* h_b = h_f + (size_t)Tn * Bn * 128;
    float* feats = (float*)(h_b + (size_t)Tn * Bn * 128);

    k_inproj<<<dim3(512, 4, 2), 256, 0, stream>>>(sent, embed,
        w_ih_f, b_ih_f, b_hh_f, w_ih_b, b_ih_b, b_hh_b, G_f, G_b);
    k_lstm<<<dim3(64, 2), 512, 0, stream>>>(w_hh_f, w_hh_b, G_f, G_b, h_f, h_b);
    k_feats<<<256, 256, 0, stream>>>(h_f, h_b, w_out, b_out, feats);
    k_viterbi<<<64, 64, 0, stream>>>(feats, trans, out);
}

// Round 10
// 1040.399 us; speedup vs baseline: 2.0812x; 1.0076x over previous
//
#include <hip/hip_runtime.h>
#include <hip/hip_bf16.h>

#define Tn 1024
#define Bn 64
#define En 128
#define G4 512
#define NEGV -10000.0f

typedef _Float16 h8v __attribute__((ext_vector_type(8)));
typedef short bh8 __attribute__((ext_vector_type(8)));
typedef float fl4 __attribute__((ext_vector_type(4)));

// ---------- bf16 helpers ----------
__device__ __forceinline__ float bf2f(unsigned short u) {
    unsigned int v = ((unsigned int)u) << 16;
    float f;
    __builtin_memcpy(&f, &v, 4);
    return f;
}
__device__ __forceinline__ unsigned short f2bf(float f) {
    unsigned int u;
    __builtin_memcpy(&u, &f, 4);
    u = (u + 0x7fffu + ((u >> 16) & 1u)) >> 16;
    return (unsigned short)u;
}

__device__ __forceinline__ float sigf(float x) { return 1.0f / (1.0f + __expf(-x)); }
__device__ __forceinline__ float tanhfast(float x) { return 1.0f - 2.0f / (1.0f + __expf(2.0f * x)); }

// lgkm-only barrier: LDS visibility without draining vmcnt.
// imm 0xC07F = vmcnt(63) expcnt(7) lgkmcnt(0).
__device__ __forceinline__ void barrier_lds_only() {
    __builtin_amdgcn_s_waitcnt(0xC07F);
    __builtin_amdgcn_s_barrier();
}

// =====================================================================
// K0: one-time weight conversion whh (fp32 [512][128]) -> f16, both dirs.
// =====================================================================
__global__ __launch_bounds__(256) void k_wcvt(
    const float* __restrict__ wf, const float* __restrict__ wb,
    unsigned short* __restrict__ o)
{
    const int i = blockIdx.x * 256 + threadIdx.x;   // 0 .. 131071
    const float v = (i < 65536) ? wf[i] : wb[i - 65536];
    const _Float16 h = (_Float16)v;
    unsigned short u;
    __builtin_memcpy(&u, &h, 2);
    o[i] = u;
}

// =====================================================================
// K1: input projection via bf16 MFMA (unchanged; writes G as [t][b][g] bf16).
// =====================================================================
__global__ __launch_bounds__(256) void k_inproj(
    const int* __restrict__ sent, const float* __restrict__ embed,
    const float* __restrict__ w_ih_f, const float* __restrict__ b_ih_f, const float* __restrict__ b_hh_f,
    const float* __restrict__ w_ih_b, const float* __restrict__ b_ih_b, const float* __restrict__ b_hh_b,
    unsigned short* __restrict__ G_f, unsigned short* __restrict__ G_b)
{
    __shared__ unsigned short Asm[128][136];
    __shared__ unsigned short Bsm[128][136];
    const int tid = threadIdx.x;
    const int dir = blockIdx.z;
    const float* w_ih = dir ? w_ih_b : w_ih_f;
    const float* bi   = dir ? b_ih_b : b_ih_f;
    const float* bh   = dir ? b_hh_b : b_hh_f;
    unsigned short* Gout = dir ? G_b : G_f;

    const int mt = blockIdx.x, nt = blockIdx.y;
    const int r0 = mt * 128, n0 = nt * 128;

    const int srow = tid >> 1;
    const int ch = (tid & 1) * 64;
    {
        const int rg = r0 + srow;
        const int tt = rg >> 6, bb = rg & 63;
        const int tok = sent[bb * Tn + tt];
        const float* ar = embed + (size_t)tok * En + ch;
        const float* br = w_ih + (size_t)(n0 + srow) * En + ch;
#pragma unroll
        for (int i = 0; i < 64; i += 4) {
            float4 v = *(const float4*)(ar + i);
            *(unsigned*)&Asm[srow][ch + i]     = (unsigned)f2bf(v.x) | ((unsigned)f2bf(v.y) << 16);
            *(unsigned*)&Asm[srow][ch + i + 2] = (unsigned)f2bf(v.z) | ((unsigned)f2bf(v.w) << 16);
            float4 u = *(const float4*)(br + i);
            *(unsigned*)&Bsm[srow][ch + i]     = (unsigned)f2bf(u.x) | ((unsigned)f2bf(u.y) << 16);
            *(unsigned*)&Bsm[srow][ch + i + 2] = (unsigned)f2bf(u.z) | ((unsigned)f2bf(u.w) << 16);
        }
    }
    __syncthreads();

    const int w = tid >> 6, lane = tid & 63;
    const int ln = lane & 15, lq = lane >> 4;
    const int nwb = w * 32;

    fl4 acc[8][2];
#pragma unroll
    for (int mi = 0; mi < 8; ++mi)
#pragma unroll
        for (int ni = 0; ni < 2; ++ni) acc[mi][ni] = (fl4){0.f, 0.f, 0.f, 0.f};

#pragma unroll
    for (int kt = 0; kt < 4; ++kt) {
        const int kc = kt * 32 + lq * 8;
        bh8 a[8], bf[2];
#pragma unroll
        for (int mi = 0; mi < 8; ++mi) a[mi] = *(const bh8*)&Asm[mi * 16 + ln][kc];
#pragma unroll
        for (int ni = 0; ni < 2; ++ni) bf[ni] = *(const bh8*)&Bsm[nwb + ni * 16 + ln][kc];
#pragma unroll
        for (int mi = 0; mi < 8; ++mi)
#pragma unroll
            for (int ni = 0; ni < 2; ++ni)
                acc[mi][ni] = __builtin_amdgcn_mfma_f32_16x16x32_bf16(a[mi], bf[ni], acc[mi][ni], 0, 0, 0);
    }

    float bias[2];
#pragma unroll
    for (int ni = 0; ni < 2; ++ni) {
        int n = n0 + nwb + ni * 16 + ln;
        bias[ni] = bi[n] + bh[n];
    }
#pragma unroll
    for (int mi = 0; mi < 8; ++mi)
#pragma unroll
        for (int ni = 0; ni < 2; ++ni) {
            const int n = n0 + nwb + ni * 16 + ln;
#pragma unroll
            for (int rg = 0; rg < 4; ++rg) {
                const int m = mi * 16 + lq * 4 + rg;
                const size_t r = (size_t)(r0 + m);
                Gout[(r << 9) + n] = f2bf(acc[mi][ni][rg] + bias[ni]);
            }
        }
}

// =====================================================================
// K2: LSTM recurrence, operand-swapped MFMA (R9 structure) + REGISTER-PINNED
// PRE-CONVERTED f16 WEIGHTS (the R10 fix).
// R9's VGPR_Count=72 proved Wf was rematerialized every step (~200 VALU
// instrs/wave/step of reload+cvt — matches measured VALUBusy). Fix:
//  (1) weights pre-converted to f16 by k_wcvt (remat would be a pure 16B load),
//  (2) 16 individually-named h8v vars, straight-line MFMA block, NO array
//      copies (R5's mistake), asm "+v" pin each step -> 64 VGPRs forced live.
// =====================================================================
__global__ __launch_bounds__(512, 2) void k_lstm(
    const unsigned short* __restrict__ whh16,
    const unsigned short* __restrict__ G_f, const unsigned short* __restrict__ G_b,
    unsigned short* __restrict__ h_f, unsigned short* __restrict__ h_b)
{
    const int tid = threadIdx.x;
    const int w = tid >> 6;
    const int lane = tid & 63;
    const int ln = lane & 15;
    const int quad = lane >> 4;
    const int b = blockIdx.x;           // batch (one per WG)
    const int dir = blockIdx.y;
    const unsigned short* Gd = dir ? G_b : G_f;
    unsigned short* ho = dir ? h_b : h_f;

    const int j = w * 16 + ln;          // this lane's h index (gate column)
    const int ko = quad * 8;            // k-offset within fragment

    __shared__ __align__(16) unsigned short hls[2][128];   // f16 h, double-buffered

    // ---- weights (B-frags) from pre-converted f16: w(q)(kt), 16 named vars ----
    const unsigned short* wb16 = whh16 + (size_t)dir * 65536;
    const unsigned short* wr0 = wb16 + ((size_t)(0 * 128 + j) << 7) + ko;
    const unsigned short* wr1 = wb16 + ((size_t)(1 * 128 + j) << 7) + ko;
    const unsigned short* wr2 = wb16 + ((size_t)(2 * 128 + j) << 7) + ko;
    const unsigned short* wr3 = wb16 + ((size_t)(3 * 128 + j) << 7) + ko;
    h8v w00 = *(const h8v*)(wr0 +  0), w01 = *(const h8v*)(wr0 + 32),
        w02 = *(const h8v*)(wr0 + 64), w03 = *(const h8v*)(wr0 + 96);
    h8v w10 = *(const h8v*)(wr1 +  0), w11 = *(const h8v*)(wr1 + 32),
        w12 = *(const h8v*)(wr1 + 64), w13 = *(const h8v*)(wr1 + 96);
    h8v w20 = *(const h8v*)(wr2 +  0), w21 = *(const h8v*)(wr2 + 32),
        w22 = *(const h8v*)(wr2 + 64), w23 = *(const h8v*)(wr2 + 96);
    h8v w30 = *(const h8v*)(wr3 +  0), w31 = *(const h8v*)(wr3 + 32),
        w32 = *(const h8v*)(wr3 + 64), w33 = *(const h8v*)(wr3 + 96);

    // zero both h buffers (2*128 f16 = 128 dwords)
    if (tid < 128) ((unsigned*)hls)[tid] = 0u;
    float c = 0.0f;
    __syncthreads();

    // ---- G pipeline preload: slot u holds the 4 gate pre-acts of step u ----
    unsigned short gp[4][4];
#pragma unroll
    for (int u = 0; u < 4; ++u) {
        const int tt = dir ? (Tn - 1 - u) : u;
        const unsigned short* gpp = Gd + (((size_t)tt * Bn + b) << 9) + j;
#pragma unroll
        for (int q = 0; q < 4; ++q) gp[u][q] = gpp[q * 128];
    }

    for (int blk = 0; blk < Tn / 4; ++blk) {
#pragma unroll
        for (int u = 0; u < 4; ++u) {
            const int s = blk * 4 + u;
            const int t = dir ? (Tn - 1 - s) : s;
            const int p = u & 1;          // h buffer parity (blk*4 is even)

            // Pin the 64 weight VGPRs live across the loop (no remat possible).
            asm volatile("" : "+v"(w00), "+v"(w01), "+v"(w02), "+v"(w03),
                              "+v"(w10), "+v"(w11), "+v"(w12), "+v"(w13),
                              "+v"(w20), "+v"(w21), "+v"(w22), "+v"(w23),
                              "+v"(w30), "+v"(w31), "+v"(w32), "+v"(w33));

            // consume slot u (loaded at step s-4; vmcnt wait finds it done)
            const unsigned short ga0 = gp[u][0], ga1 = gp[u][1];
            const unsigned short ga2 = gp[u][2], ga3 = gp[u][3];

            // prefetch step s+4 into slot u (static index -> no copies)
            if (s + 4 < Tn) {
                const int tt = dir ? (Tn - 1 - (s + 4)) : (s + 4);
                const unsigned short* gpp = Gd + (((size_t)tt * Bn + b) << 9) + j;
#pragma unroll
                for (int q = 0; q < 4; ++q) gp[u][q] = gpp[q * 128];
            }

            // ---- MFMA (operands swapped, straight-line): acc q = dot(h, W[q*128+j])
            const unsigned short* hrow = &hls[p][ko];
            h8v hx0 = *(const h8v*)(hrow +  0);
            h8v hx1 = *(const h8v*)(hrow + 32);
            h8v hx2 = *(const h8v*)(hrow + 64);
            h8v hx3 = *(const h8v*)(hrow + 96);

            fl4 a0 = (fl4){0.f, 0.f, 0.f, 0.f};
            fl4 a1 = (fl4){0.f, 0.f, 0.f, 0.f};
            fl4 a2 = (fl4){0.f, 0.f, 0.f, 0.f};
            fl4 a3 = (fl4){0.f, 0.f, 0.f, 0.f};
            a0 = __builtin_amdgcn_mfma_f32_16x16x32_f16(hx0, w00, a0, 0, 0, 0);
            a1 = __builtin_amdgcn_mfma_f32_16x16x32_f16(hx0, w10, a1, 0, 0, 0);
            a2 = __builtin_amdgcn_mfma_f32_16x16x32_f16(hx0, w20, a2, 0, 0, 0);
            a3 = __builtin_amdgcn_mfma_f32_16x16x32_f16(hx0, w30, a3, 0, 0, 0);
            a0 = __builtin_amdgcn_mfma_f32_16x16x32_f16(hx1, w01, a0, 0, 0, 0);
            a1 = __builtin_amdgcn_mfma_f32_16x16x32_f16(hx1, w11, a1, 0, 0, 0);
            a2 = __builtin_amdgcn_mfma_f32_16x16x32_f16(hx1, w21, a2, 0, 0, 0);
            a3 = __builtin_amdgcn_mfma_f32_16x16x32_f16(hx1, w31, a3, 0, 0, 0);
            a0 = __builtin_amdgcn_mfma_f32_16x16x32_f16(hx2, w02, a0, 0, 0, 0);
            a1 = __builtin_amdgcn_mfma_f32_16x16x32_f16(hx2, w12, a1, 0, 0, 0);
            a2 = __builtin_amdgcn_mfma_f32_16x16x32_f16(hx2, w22, a2, 0, 0, 0);
            a3 = __builtin_amdgcn_mfma_f32_16x16x32_f16(hx2, w32, a3, 0, 0, 0);
            a0 = __builtin_amdgcn_mfma_f32_16x16x32_f16(hx3, w03, a0, 0, 0, 0);
            a1 = __builtin_amdgcn_mfma_f32_16x16x32_f16(hx3, w13, a1, 0, 0, 0);
            a2 = __builtin_amdgcn_mfma_f32_16x16x32_f16(hx3, w23, a2, 0, 0, 0);
            a3 = __builtin_amdgcn_mfma_f32_16x16x32_f16(hx3, w33, a3, 0, 0, 0);

            // ---- activation: ONE h-element per lane (replicated across quads) ----
            float pi = a0[0] + bf2f(ga0);
            float pf = a1[0] + bf2f(ga1);
            float pg = a2[0] + bf2f(ga2);
            float po = a3[0] + bf2f(ga3);
            float iv = sigf(pi), fv = sigf(pf), gv = tanhfast(pg), ov = sigf(po);
            c = fv * c + iv * gv;
            float hn = ov * tanhfast(c);

            // ---- h writes (quad==0 lanes: 128 lanes cover all j): LDS f16 + global bf16
            if (quad == 0) {
                _Float16 hf16 = (_Float16)hn;
                unsigned short hu;
                __builtin_memcpy(&hu, &hf16, 2);
                hls[1 - p][j] = hu;
                ho[(((size_t)t * Bn + b) << 7) + j] = f2bf(hn);
            }

            barrier_lds_only();
        }
    }
}

// =====================================================================
// K3: feats (unchanged).
// =====================================================================
__global__ __launch_bounds__(256) void k_feats(
    const unsigned short* __restrict__ h_f, const unsigned short* __restrict__ h_b,
    const float* __restrict__ w_out, const float* __restrict__ b_out,
    float* __restrict__ feats)
{
    __shared__ float wl[256][12];
    __shared__ float bl[12];
    const int tid = threadIdx.x;
#pragma unroll
    for (int s = 0; s < 9; ++s) wl[tid][s] = w_out[s * 256 + tid];
#pragma unroll
    for (int s = 9; s < 12; ++s) wl[tid][s] = 0.0f;
    if (tid < 12) bl[tid] = (tid < 9) ? b_out[tid] : 0.0f;
    __syncthreads();

    const int r = blockIdx.x * 256 + tid;
    const unsigned short* hfr = h_f + (size_t)r * 128;
    const unsigned short* hbr = h_b + (size_t)r * 128;
    float acc[12];
#pragma unroll
    for (int k = 0; k < 12; ++k) acc[k] = bl[k];

    for (int ch = 0; ch < 32; ++ch) {
        const unsigned short* src = (ch < 16) ? (hfr + ch * 8) : (hbr + (ch - 16) * 8);
        uint4 hv = *(const uint4*)src;
        unsigned int hw0 = hv.x, hw1 = hv.y, hw2 = hv.z, hw3 = hv.w;
        const int jb = ch * 8;
#pragma unroll
        for (int q = 0; q < 8; ++q) {
            unsigned int word = (q < 2) ? hw0 : ((q < 4) ? hw1 : ((q < 6) ? hw2 : hw3));
            unsigned short hs = (q & 1) ? (unsigned short)(word >> 16) : (unsigned short)(word & 0xffff);
            float hf = bf2f(hs);
            const float* wrp = &wl[jb + q][0];
            float4 w0 = *(const float4*)(wrp);
            float4 w1 = *(const float4*)(wrp + 4);
            float4 w2 = *(const float4*)(wrp + 8);
            acc[0] += hf * w0.x; acc[1] += hf * w0.y; acc[2] += hf * w0.z; acc[3] += hf * w0.w;
            acc[4] += hf * w1.x; acc[5] += hf * w1.y; acc[6] += hf * w1.z; acc[7] += hf * w1.w;
            acc[8] += hf * w2.x; acc[9] += hf * w2.y; acc[10] += hf * w2.z; acc[11] += hf * w2.w;
        }
    }
    float* fr = feats + (size_t)r * 9;
#pragma unroll
    for (int k = 0; k < 9; ++k) fr[k] = acc[k];
}

// =====================================================================
// K4: Viterbi (unchanged).
// =====================================================================
__global__ __launch_bounds__(64) void k_viterbi(
    const float* __restrict__ feats, const float* __restrict__ trans,
    float* __restrict__ out)
{
    __shared__ __align__(16) unsigned char bp[1024 * 16];
    __shared__ float fl[1024 * 9];
    __shared__ float dl[12];
    __shared__ unsigned char pt[1024];

    const int b = blockIdx.x, tid = threadIdx.x;

    for (int i = tid; i < 9216; i += 64) {
        int t = i / 9;
        int n = i - t * 9;
        fl[i] = feats[((size_t)t * 64 + b) * 9 + n];
    }

    float tr[9];
    float trs = -3.0e38f;
    if (tid < 9) {
#pragma unroll
        for (int p = 0; p < 9; ++p) tr[p] = trans[tid * 9 + p];
        trs = trans[8 * 9 + tid];
    }
    if (tid < 12) dl[tid] = (tid == 7) ? 0.0f : NEGV;
    __syncthreads();

    if (tid < 9) {
        for (int t = 0; t < 1024; ++t) {
            float4 d0 = *(const float4*)&dl[0];
            float4 d1 = *(const float4*)&dl[4];
            float d8 = dl[8];
            float dv0 = d0.x, dv1 = d0.y, dv2 = d0.z, dv3 = d0.w;
            float dv4 = d1.x, dv5 = d1.y, dv6 = d1.z, dv7 = d1.w;
            float m = dv0 + tr[0]; int am = 0;
            float v;
            v = dv1 + tr[1]; if (v > m) { m = v; am = 1; }
            v = dv2 + tr[2]; if (v > m) { m = v; am = 2; }
            v = dv3 + tr[3]; if (v > m) { m = v; am = 3; }
            v = dv4 + tr[4]; if (v > m) { m = v; am = 4; }
            v = dv5 + tr[5]; if (v > m) { m = v; am = 5; }
            v = dv6 + tr[6]; if (v > m) { m = v; am = 6; }
            v = dv7 + tr[7]; if (v > m) { m = v; am = 7; }
            v = d8  + tr[8]; if (v > m) { m = v; am = 8; }
            float nd = m + fl[t * 9 + tid];
            dl[tid] = nd;
            bp[t * 16 + tid] = (unsigned char)am;
        }
    }
    float tv = (tid < 9) ? (dl[tid] + trs) : -3.0e38f;
    int bi = tid;
#pragma unroll
    for (int off = 8; off >= 1; off >>= 1) {
        float ov = __shfl_down(tv, off, 64);
        int oi = __shfl_down(bi, off, 64);
        if (ov > tv || (ov == tv && oi < bi)) { tv = ov; bi = oi; }
    }
    int best = __shfl(bi, 0, 64);
    if (tid == 0) out[b] = tv;

    if (tid == 0) {
        int tag = best;
        for (int t0 = 1023; t0 >= 0; t0 -= 8) {
            uint4 rows[8];
#pragma unroll
            for (int i = 0; i < 8; ++i) rows[i] = *(const uint4*)&bp[(t0 - i) * 16];
#pragma unroll
            for (int i = 0; i < 8; ++i) {
                pt[t0 - i] = (unsigned char)tag;
                uint4 rw = rows[i];
                unsigned int sel = (unsigned int)tag >> 2;
                unsigned int word = (sel == 0) ? rw.x : ((sel == 1) ? rw.y : rw.z);
                tag = (int)((word >> ((tag & 3) * 8)) & 0xffu);
            }
        }
    }
    for (int i = tid; i < 1024; i += 64) {
        out[64 + b * 1024 + i] = (float)pt[i];
    }
}

// =====================================================================
extern "C" void kernel_launch(void* const* d_in, const int* in_sizes, int n_in,
                              void* d_out, int out_size, void* d_ws, size_t ws_size,
                              hipStream_t stream) {
    const int*   sent   = (const int*)d_in[0];
    const float* embed  = (const float*)d_in[1];
    const float* w_ih_f = (const float*)d_in[2];
    const float* w_hh_f = (const float*)d_in[3];
    const float* b_ih_f = (const float*)d_in[4];
    const float* b_hh_f = (const float*)d_in[5];
    const float* w_ih_b = (const float*)d_in[6];
    const float* w_hh_b = (const float*)d_in[7];
    const float* b_ih_b = (const float*)d_in[8];
    const float* b_hh_b = (const float*)d_in[9];
    const float* w_out  = (const float*)d_in[10];
    const float* b_out  = (const float*)d_in[11];
    const float* trans  = (const float*)d_in[12];
    float* out = (float*)d_out;

    unsigned short* G_f = (unsigned short*)d_ws;
    unsigned short* G_b = G_f + (size_t)Tn * Bn * G4;
    unsigned short* h_f = G_b + (size_t)Tn * Bn * G4;
    unsigned short* h_b = h_f + (size_t)Tn * Bn * 128;
    float* feats = (float*)(h_b + (size_t)Tn * Bn * 128);
    unsigned short* whh16 = (unsigned short*)(feats + (size_t)Tn * Bn * 9);

    k_wcvt<<<512, 256, 0, stream>>>(w_hh_f, w_hh_b, whh16);
    k_inproj<<<dim3(512, 4, 2), 256, 0, stream>>>(sent, embed,
        w_ih_f, b_ih_f, b_hh_f, w_ih_b, b_ih_b, b_hh_b, G_f, G_b);
    k_lstm<<<dim3(64, 2), 512, 0, stream>>>(whh16, G_f, G_b, h_f, h_b);
    k_feats<<<256, 256, 0, stream>>>(h_f, h_b, w_out, b_out, feats);
    k_viterbi<<<64, 64, 0, stream>>>(feats, trans, out);
}

// Round 11
// 1038.409 us; speedup vs baseline: 2.0852x; 1.0019x over previous
//
#include <hip/hip_runtime.h>
#include <hip/hip_bf16.h>

#define Tn 1024
#define Bn 64
#define En 128
#define G4 512
#define NEGV -10000.0f

typedef _Float16 h8v __attribute__((ext_vector_type(8)));
typedef short bh8 __attribute__((ext_vector_type(8)));
typedef float fl4 __attribute__((ext_vector_type(4)));

// ---------- bf16 helpers ----------
__device__ __forceinline__ float bf2f(unsigned short u) {
    unsigned int v = ((unsigned int)u) << 16;
    float f;
    __builtin_memcpy(&f, &v, 4);
    return f;
}
__device__ __forceinline__ unsigned short f2bf(float f) {
    unsigned int u;
    __builtin_memcpy(&u, &f, 4);
    u = (u + 0x7fffu + ((u >> 16) & 1u)) >> 16;
    return (unsigned short)u;
}

__device__ __forceinline__ float sigf(float x) { return 1.0f / (1.0f + __expf(-x)); }
__device__ __forceinline__ float tanhfast(float x) { return 1.0f - 2.0f / (1.0f + __expf(2.0f * x)); }

// lgkm-only barrier: LDS visibility without draining vmcnt.
// imm 0xC07F = vmcnt(63) expcnt(7) lgkmcnt(0).
__device__ __forceinline__ void barrier_lds_only() {
    __builtin_amdgcn_s_waitcnt(0xC07F);
    __builtin_amdgcn_s_barrier();
}

// =====================================================================
// K0: one-time weight conversion whh (fp32 [512][128]) -> f16, both dirs.
// =====================================================================
__global__ __launch_bounds__(256) void k_wcvt(
    const float* __restrict__ wf, const float* __restrict__ wb,
    unsigned short* __restrict__ o)
{
    const int i = blockIdx.x * 256 + threadIdx.x;   // 0 .. 131071
    const float v = (i < 65536) ? wf[i] : wb[i - 65536];
    const _Float16 h = (_Float16)v;
    unsigned short u;
    __builtin_memcpy(&u, &h, 2);
    o[i] = u;
}

// =====================================================================
// K1: input projection via bf16 MFMA (unchanged; writes G as [t][b][g] bf16).
// =====================================================================
__global__ __launch_bounds__(256) void k_inproj(
    const int* __restrict__ sent, const float* __restrict__ embed,
    const float* __restrict__ w_ih_f, const float* __restrict__ b_ih_f, const float* __restrict__ b_hh_f,
    const float* __restrict__ w_ih_b, const float* __restrict__ b_ih_b, const float* __restrict__ b_hh_b,
    unsigned short* __restrict__ G_f, unsigned short* __restrict__ G_b)
{
    __shared__ unsigned short Asm[128][136];
    __shared__ unsigned short Bsm[128][136];
    const int tid = threadIdx.x;
    const int dir = blockIdx.z;
    const float* w_ih = dir ? w_ih_b : w_ih_f;
    const float* bi   = dir ? b_ih_b : b_ih_f;
    const float* bh   = dir ? b_hh_b : b_hh_f;
    unsigned short* Gout = dir ? G_b : G_f;

    const int mt = blockIdx.x, nt = blockIdx.y;
    const int r0 = mt * 128, n0 = nt * 128;

    const int srow = tid >> 1;
    const int ch = (tid & 1) * 64;
    {
        const int rg = r0 + srow;
        const int tt = rg >> 6, bb = rg & 63;
        const int tok = sent[bb * Tn + tt];
        const float* ar = embed + (size_t)tok * En + ch;
        const float* br = w_ih + (size_t)(n0 + srow) * En + ch;
#pragma unroll
        for (int i = 0; i < 64; i += 4) {
            float4 v = *(const float4*)(ar + i);
            *(unsigned*)&Asm[srow][ch + i]     = (unsigned)f2bf(v.x) | ((unsigned)f2bf(v.y) << 16);
            *(unsigned*)&Asm[srow][ch + i + 2] = (unsigned)f2bf(v.z) | ((unsigned)f2bf(v.w) << 16);
            float4 u = *(const float4*)(br + i);
            *(unsigned*)&Bsm[srow][ch + i]     = (unsigned)f2bf(u.x) | ((unsigned)f2bf(u.y) << 16);
            *(unsigned*)&Bsm[srow][ch + i + 2] = (unsigned)f2bf(u.z) | ((unsigned)f2bf(u.w) << 16);
        }
    }
    __syncthreads();

    const int w = tid >> 6, lane = tid & 63;
    const int ln = lane & 15, lq = lane >> 4;
    const int nwb = w * 32;

    fl4 acc[8][2];
#pragma unroll
    for (int mi = 0; mi < 8; ++mi)
#pragma unroll
        for (int ni = 0; ni < 2; ++ni) acc[mi][ni] = (fl4){0.f, 0.f, 0.f, 0.f};

#pragma unroll
    for (int kt = 0; kt < 4; ++kt) {
        const int kc = kt * 32 + lq * 8;
        bh8 a[8], bf[2];
#pragma unroll
        for (int mi = 0; mi < 8; ++mi) a[mi] = *(const bh8*)&Asm[mi * 16 + ln][kc];
#pragma unroll
        for (int ni = 0; ni < 2; ++ni) bf[ni] = *(const bh8*)&Bsm[nwb + ni * 16 + ln][kc];
#pragma unroll
        for (int mi = 0; mi < 8; ++mi)
#pragma unroll
            for (int ni = 0; ni < 2; ++ni)
                acc[mi][ni] = __builtin_amdgcn_mfma_f32_16x16x32_bf16(a[mi], bf[ni], acc[mi][ni], 0, 0, 0);
    }

    float bias[2];
#pragma unroll
    for (int ni = 0; ni < 2; ++ni) {
        int n = n0 + nwb + ni * 16 + ln;
        bias[ni] = bi[n] + bh[n];
    }
#pragma unroll
    for (int mi = 0; mi < 8; ++mi)
#pragma unroll
        for (int ni = 0; ni < 2; ++ni) {
            const int n = n0 + nwb + ni * 16 + ln;
#pragma unroll
            for (int rg = 0; rg < 4; ++rg) {
                const int m = mi * 16 + lq * 4 + rg;
                const size_t r = (size_t)(r0 + m);
                Gout[(r << 9) + n] = f2bf(acc[mi][ni][rg] + bias[ni]);
            }
        }
}

// =====================================================================
// K2: LSTM recurrence, operand-swapped MFMA (R9 structure).
// R10 post-mortem: the per-step asm "+v" pin forced the AGPR-resident
// weights into VGPRs every iteration (~128 v_accvgpr copies/step — matches
// VALUBusy arithmetic exactly). R11 fix: NO pin; instead the 16 weight
// fragments are produced by opaque `asm volatile` global_load_dwordx4 —
// asm-produced values cannot be rematerialized, so the compiler must keep
// them register-resident (VGPR or AGPR, MFMA reads both) for the whole
// 1024-step loop with ZERO per-step cost. One manual s_waitcnt vmcnt(0)
// completes them before use (the compiler does not track asm loads).
// =====================================================================
__global__ __launch_bounds__(512, 2) void k_lstm(
    const unsigned short* __restrict__ whh16,
    const unsigned short* __restrict__ G_f, const unsigned short* __restrict__ G_b,
    unsigned short* __restrict__ h_f, unsigned short* __restrict__ h_b)
{
    const int tid = threadIdx.x;
    const int w = tid >> 6;
    const int lane = tid & 63;
    const int ln = lane & 15;
    const int quad = lane >> 4;
    const int b = blockIdx.x;           // batch (one per WG)
    const int dir = blockIdx.y;
    const unsigned short* Gd = dir ? G_b : G_f;
    unsigned short* ho = dir ? h_b : h_f;

    const int j = w * 16 + ln;          // this lane's h index (gate column)
    const int ko = quad * 8;            // k-offset within fragment

    __shared__ __align__(16) unsigned short hls[2][128];   // f16 h, double-buffered

    // ---- weights (B-frags) via opaque asm loads: not rematerializable ----
    const unsigned short* wb16 = whh16 + (size_t)dir * 65536;
    const unsigned short* wr0 = wb16 + ((size_t)(0 * 128 + j) << 7) + ko;
    const unsigned short* wr1 = wb16 + ((size_t)(1 * 128 + j) << 7) + ko;
    const unsigned short* wr2 = wb16 + ((size_t)(2 * 128 + j) << 7) + ko;
    const unsigned short* wr3 = wb16 + ((size_t)(3 * 128 + j) << 7) + ko;
    h8v w00, w01, w02, w03, w10, w11, w12, w13, w20, w21, w22, w23, w30, w31, w32, w33;
    asm volatile("global_load_dwordx4 %0, %1, off"            : "=v"(w00) : "v"(wr0));
    asm volatile("global_load_dwordx4 %0, %1, off offset:64"  : "=v"(w01) : "v"(wr0));
    asm volatile("global_load_dwordx4 %0, %1, off offset:128" : "=v"(w02) : "v"(wr0));
    asm volatile("global_load_dwordx4 %0, %1, off offset:192" : "=v"(w03) : "v"(wr0));
    asm volatile("global_load_dwordx4 %0, %1, off"            : "=v"(w10) : "v"(wr1));
    asm volatile("global_load_dwordx4 %0, %1, off offset:64"  : "=v"(w11) : "v"(wr1));
    asm volatile("global_load_dwordx4 %0, %1, off offset:128" : "=v"(w12) : "v"(wr1));
    asm volatile("global_load_dwordx4 %0, %1, off offset:192" : "=v"(w13) : "v"(wr1));
    asm volatile("global_load_dwordx4 %0, %1, off"            : "=v"(w20) : "v"(wr2));
    asm volatile("global_load_dwordx4 %0, %1, off offset:64"  : "=v"(w21) : "v"(wr2));
    asm volatile("global_load_dwordx4 %0, %1, off offset:128" : "=v"(w22) : "v"(wr2));
    asm volatile("global_load_dwordx4 %0, %1, off offset:192" : "=v"(w23) : "v"(wr2));
    asm volatile("global_load_dwordx4 %0, %1, off"            : "=v"(w30) : "v"(wr3));
    asm volatile("global_load_dwordx4 %0, %1, off offset:64"  : "=v"(w31) : "v"(wr3));
    asm volatile("global_load_dwordx4 %0, %1, off offset:128" : "=v"(w32) : "v"(wr3));
    asm volatile("global_load_dwordx4 %0, %1, off offset:192" : "=v"(w33) : "v"(wr3));
    asm volatile("s_waitcnt vmcnt(0)" ::: "memory");

    // zero both h buffers (2*128 f16 = 128 dwords)
    if (tid < 128) ((unsigned*)hls)[tid] = 0u;
    float c = 0.0f;
    __syncthreads();

    // ---- G pipeline preload: slot u holds the 4 gate pre-acts of step u ----
    unsigned short gp[4][4];
#pragma unroll
    for (int u = 0; u < 4; ++u) {
        const int tt = dir ? (Tn - 1 - u) : u;
        const unsigned short* gpp = Gd + (((size_t)tt * Bn + b) << 9) + j;
#pragma unroll
        for (int q = 0; q < 4; ++q) gp[u][q] = gpp[q * 128];
    }

    for (int blk = 0; blk < Tn / 4; ++blk) {
#pragma unroll
        for (int u = 0; u < 4; ++u) {
            const int s = blk * 4 + u;
            const int t = dir ? (Tn - 1 - s) : s;
            const int p = u & 1;          // h buffer parity (blk*4 is even)

            // consume slot u (loaded at step s-4; vmcnt wait finds it done)
            const unsigned short ga0 = gp[u][0], ga1 = gp[u][1];
            const unsigned short ga2 = gp[u][2], ga3 = gp[u][3];

            // prefetch step s+4 into slot u (static index -> no copies)
            if (s + 4 < Tn) {
                const int tt = dir ? (Tn - 1 - (s + 4)) : (s + 4);
                const unsigned short* gpp = Gd + (((size_t)tt * Bn + b) << 9) + j;
#pragma unroll
                for (int q = 0; q < 4; ++q) gp[u][q] = gpp[q * 128];
            }

            // ---- MFMA (operands swapped, straight-line): acc q = dot(h, W[q*128+j])
            const unsigned short* hrow = &hls[p][ko];
            h8v hx0 = *(const h8v*)(hrow +  0);
            h8v hx1 = *(const h8v*)(hrow + 32);
            h8v hx2 = *(const h8v*)(hrow + 64);
            h8v hx3 = *(const h8v*)(hrow + 96);

            fl4 a0 = (fl4){0.f, 0.f, 0.f, 0.f};
            fl4 a1 = (fl4){0.f, 0.f, 0.f, 0.f};
            fl4 a2 = (fl4){0.f, 0.f, 0.f, 0.f};
            fl4 a3 = (fl4){0.f, 0.f, 0.f, 0.f};
            a0 = __builtin_amdgcn_mfma_f32_16x16x32_f16(hx0, w00, a0, 0, 0, 0);
            a1 = __builtin_amdgcn_mfma_f32_16x16x32_f16(hx0, w10, a1, 0, 0, 0);
            a2 = __builtin_amdgcn_mfma_f32_16x16x32_f16(hx0, w20, a2, 0, 0, 0);
            a3 = __builtin_amdgcn_mfma_f32_16x16x32_f16(hx0, w30, a3, 0, 0, 0);
            a0 = __builtin_amdgcn_mfma_f32_16x16x32_f16(hx1, w01, a0, 0, 0, 0);
            a1 = __builtin_amdgcn_mfma_f32_16x16x32_f16(hx1, w11, a1, 0, 0, 0);
            a2 = __builtin_amdgcn_mfma_f32_16x16x32_f16(hx1, w21, a2, 0, 0, 0);
            a3 = __builtin_amdgcn_mfma_f32_16x16x32_f16(hx1, w31, a3, 0, 0, 0);
            a0 = __builtin_amdgcn_mfma_f32_16x16x32_f16(hx2, w02, a0, 0, 0, 0);
            a1 = __builtin_amdgcn_mfma_f32_16x16x32_f16(hx2, w12, a1, 0, 0, 0);
            a2 = __builtin_amdgcn_mfma_f32_16x16x32_f16(hx2, w22, a2, 0, 0, 0);
            a3 = __builtin_amdgcn_mfma_f32_16x16x32_f16(hx2, w32, a3, 0, 0, 0);
            a0 = __builtin_amdgcn_mfma_f32_16x16x32_f16(hx3, w03, a0, 0, 0, 0);
            a1 = __builtin_amdgcn_mfma_f32_16x16x32_f16(hx3, w13, a1, 0, 0, 0);
            a2 = __builtin_amdgcn_mfma_f32_16x16x32_f16(hx3, w23, a2, 0, 0, 0);
            a3 = __builtin_amdgcn_mfma_f32_16x16x32_f16(hx3, w33, a3, 0, 0, 0);

            // ---- activation: ONE h-element per lane (replicated across quads) ----
            float pi = a0[0] + bf2f(ga0);
            float pf = a1[0] + bf2f(ga1);
            float pg = a2[0] + bf2f(ga2);
            float po = a3[0] + bf2f(ga3);
            float iv = sigf(pi), fv = sigf(pf), gv = tanhfast(pg), ov = sigf(po);
            c = fv * c + iv * gv;
            float hn = ov * tanhfast(c);

            // ---- h writes (quad==0 lanes: 128 lanes cover all j): LDS f16 + global bf16
            if (quad == 0) {
                _Float16 hf16 = (_Float16)hn;
                unsigned short hu;
                __builtin_memcpy(&hu, &hf16, 2);
                hls[1 - p][j] = hu;
                ho[(((size_t)t * Bn + b) << 7) + j] = f2bf(hn);
            }

            barrier_lds_only();
        }
    }
}

// =====================================================================
// K3: feats (unchanged).
// =====================================================================
__global__ __launch_bounds__(256) void k_feats(
    const unsigned short* __restrict__ h_f, const unsigned short* __restrict__ h_b,
    const float* __restrict__ w_out, const float* __restrict__ b_out,
    float* __restrict__ feats)
{
    __shared__ float wl[256][12];
    __shared__ float bl[12];
    const int tid = threadIdx.x;
#pragma unroll
    for (int s = 0; s < 9; ++s) wl[tid][s] = w_out[s * 256 + tid];
#pragma unroll
    for (int s = 9; s < 12; ++s) wl[tid][s] = 0.0f;
    if (tid < 12) bl[tid] = (tid < 9) ? b_out[tid] : 0.0f;
    __syncthreads();

    const int r = blockIdx.x * 256 + tid;
    const unsigned short* hfr = h_f + (size_t)r * 128;
    const unsigned short* hbr = h_b + (size_t)r * 128;
    float acc[12];
#pragma unroll
    for (int k = 0; k < 12; ++k) acc[k] = bl[k];

    for (int ch = 0; ch < 32; ++ch) {
        const unsigned short* src = (ch < 16) ? (hfr + ch * 8) : (hbr + (ch - 16) * 8);
        uint4 hv = *(const uint4*)src;
        unsigned int hw0 = hv.x, hw1 = hv.y, hw2 = hv.z, hw3 = hv.w;
        const int jb = ch * 8;
#pragma unroll
        for (int q = 0; q < 8; ++q) {
            unsigned int word = (q < 2) ? hw0 : ((q < 4) ? hw1 : ((q < 6) ? hw2 : hw3));
            unsigned short hs = (q & 1) ? (unsigned short)(word >> 16) : (unsigned short)(word & 0xffff);
            float hf = bf2f(hs);
            const float* wrp = &wl[jb + q][0];
            float4 w0 = *(const float4*)(wrp);
            float4 w1 = *(const float4*)(wrp + 4);
            float4 w2 = *(const float4*)(wrp + 8);
            acc[0] += hf * w0.x; acc[1] += hf * w0.y; acc[2] += hf * w0.z; acc[3] += hf * w0.w;
            acc[4] += hf * w1.x; acc[5] += hf * w1.y; acc[6] += hf * w1.z; acc[7] += hf * w1.w;
            acc[8] += hf * w2.x; acc[9] += hf * w2.y; acc[10] += hf * w2.z; acc[11] += hf * w2.w;
        }
    }
    float* fr = feats + (size_t)r * 9;
#pragma unroll
    for (int k = 0; k < 9; ++k) fr[k] = acc[k];
}

// =====================================================================
// K4: Viterbi (unchanged).
// =====================================================================
__global__ __launch_bounds__(64) void k_viterbi(
    const float* __restrict__ feats, const float* __restrict__ trans,
    float* __restrict__ out)
{
    __shared__ __align__(16) unsigned char bp[1024 * 16];
    __shared__ float fl[1024 * 9];
    __shared__ float dl[12];
    __shared__ unsigned char pt[1024];

    const int b = blockIdx.x, tid = threadIdx.x;

    for (int i = tid; i < 9216; i += 64) {
        int t = i / 9;
        int n = i - t * 9;
        fl[i] = feats[((size_t)t * 64 + b) * 9 + n];
    }

    float tr[9];
    float trs = -3.0e38f;
    if (tid < 9) {
#pragma unroll
        for (int p = 0; p < 9; ++p) tr[p] = trans[tid * 9 + p];
        trs = trans[8 * 9 + tid];
    }
    if (tid < 12) dl[tid] = (tid == 7) ? 0.0f : NEGV;
    __syncthreads();

    if (tid < 9) {
        for (int t = 0; t < 1024; ++t) {
            float4 d0 = *(const float4*)&dl[0];
            float4 d1 = *(const float4*)&dl[4];
            float d8 = dl[8];
            float dv0 = d0.x, dv1 = d0.y, dv2 = d0.z, dv3 = d0.w;
            float dv4 = d1.x, dv5 = d1.y, dv6 = d1.z, dv7 = d1.w;
            float m = dv0 + tr[0]; int am = 0;
            float v;
            v = dv1 + tr[1]; if (v > m) { m = v; am = 1; }
            v = dv2 + tr[2]; if (v > m) { m = v; am = 2; }
            v = dv3 + tr[3]; if (v > m) { m = v; am = 3; }
            v = dv4 + tr[4]; if (v > m) { m = v; am = 4; }
            v = dv5 + tr[5]; if (v > m) { m = v; am = 5; }
            v = dv6 + tr[6]; if (v > m) { m = v; am = 6; }
            v = dv7 + tr[7]; if (v > m) { m = v; am = 7; }
            v = d8  + tr[8]; if (v > m) { m = v; am = 8; }
            float nd = m + fl[t * 9 + tid];
            dl[tid] = nd;
            bp[t * 16 + tid] = (unsigned char)am;
        }
    }
    float tv = (tid < 9) ? (dl[tid] + trs) : -3.0e38f;
    int bi = tid;
#pragma unroll
    for (int off = 8; off >= 1; off >>= 1) {
        float ov = __shfl_down(tv, off, 64);
        int oi = __shfl_down(bi, off, 64);
        if (ov > tv || (ov == tv && oi < bi)) { tv = ov; bi = oi; }
    }
    int best = __shfl(bi, 0, 64);
    if (tid == 0) out[b] = tv;

    if (tid == 0) {
        int tag = best;
        for (int t0 = 1023; t0 >= 0; t0 -= 8) {
            uint4 rows[8];
#pragma unroll
            for (int i = 0; i < 8; ++i) rows[i] = *(const uint4*)&bp[(t0 - i) * 16];
#pragma unroll
            for (int i = 0; i < 8; ++i) {
                pt[t0 - i] = (unsigned char)tag;
                uint4 rw = rows[i];
                unsigned int sel = (unsigned int)tag >> 2;
                unsigned int word = (sel == 0) ? rw.x : ((sel == 1) ? rw.y : rw.z);
                tag = (int)((word >> ((tag & 3) * 8)) & 0xffu);
            }
        }
    }
    for (int i = tid; i < 1024; i += 64) {
        out[64 + b * 1024 + i] = (float)pt[i];
    }
}

// =====================================================================
extern "C" void kernel_launch(void* const* d_in, const int* in_sizes, int n_in,
                              void* d_out, int out_size, void* d_ws, size_t ws_size,
                              hipStream_t stream) {
    const int*   sent   = (const int*)d_in[0];
    const float* embed  = (const float*)d_in[1];
    const float* w_ih_f = (const float*)d_in[2];
    const float* w_hh_f = (const float*)d_in[3];
    const float* b_ih_f = (const float*)d_in[4];
    const float* b_hh_f = (const float*)d_in[5];
    const float* w_ih_b = (const float*)d_in[6];
    const float* w_hh_b = (const float*)d_in[7];
    const float* b_ih_b = (const float*)d_in[8];
    const float* b_hh_b = (const float*)d_in[9];
    const float* w_out  = (const float*)d_in[10];
    const float* b_out  = (const float*)d_in[11];
    const float* trans  = (const float*)d_in[12];
    float* out = (float*)d_out;

    unsigned short* G_f = (unsigned short*)d_ws;
    unsigned short* G_b = G_f + (size_t)Tn * Bn * G4;
    unsigned short* h_f = G_b + (size_t)Tn * Bn * G4;
    unsigned short* h_b = h_f + (size_t)Tn * Bn * 128;
    float* feats = (float*)(h_b + (size_t)Tn * Bn * 128);
    unsigned short* whh16 = (unsigned short*)(feats + (size_t)Tn * Bn * 9);

    k_wcvt<<<512, 256, 0, stream>>>(w_hh_f, w_hh_b, whh16);
    k_inproj<<<dim3(512, 4, 2), 256, 0, stream>>>(sent, embed,
        w_ih_f, b_ih_f, b_hh_f, w_ih_b, b_ih_b, b_hh_b, G_f, G_b);
    k_lstm<<<dim3(64, 2), 512, 0, stream>>>(whh16, G_f, G_b, h_f, h_b);
    k_feats<<<256, 256, 0, stream>>>(h_f, h_b, w_out, b_out, feats);
    k_viterbi<<<64, 64, 0, stream>>>(feats, trans, out);
}

// Round 12
// 971.776 us; speedup vs baseline: 2.2281x; 1.0686x over previous
//
#include <hip/hip_runtime.h>
#include <hip/hip_bf16.h>

#define Tn 1024
#define Bn 64
#define En 128
#define G4 512
#define NEGV -10000.0f

typedef _Float16 h8v __attribute__((ext_vector_type(8)));
typedef short bh8 __attribute__((ext_vector_type(8)));
typedef float fl4 __attribute__((ext_vector_type(4)));
typedef int i8v __attribute__((ext_vector_type(8)));

// ---------- bf16 helpers ----------
__device__ __forceinline__ float bf2f(unsigned short u) {
    unsigned int v = ((unsigned int)u) << 16;
    float f;
    __builtin_memcpy(&f, &v, 4);
    return f;
}
__device__ __forceinline__ unsigned short f2bf(float f) {
    unsigned int u;
    __builtin_memcpy(&u, &f, 4);
    u = (u + 0x7fffu + ((u >> 16) & 1u)) >> 16;
    return (unsigned short)u;
}

// ---------- fp8 e4m3fn encode ----------
__device__ __forceinline__ unsigned char f8enc(float x) {
#if __has_builtin(__builtin_amdgcn_cvt_pk_fp8_f32)
    int pk = __builtin_amdgcn_cvt_pk_fp8_f32(x, 0.0f, 0, false);
    return (unsigned char)(pk & 0xff);
#else
    // manual OCP e4m3fn (RNE): max 448, min normal 2^-6, subnormal step 2^-9
    unsigned u;
    __builtin_memcpy(&u, &x, 4);
    unsigned s = (u >> 31) << 7;
    float a = fabsf(x);
    if (!(a > 0.0f)) return (unsigned char)s;
    if (a >= 464.0f) return (unsigned char)(s | 0x7E);
    if (a < 0.015625f) {                       // subnormal
        int q = (int)rintf(a * 512.0f);        // a / 2^-9 ; q in [0,8] (8 -> min normal)
        return (unsigned char)(s | (unsigned)q);
    }
    int ex;
    (void)frexpf(a, &ex);                      // a = fr * 2^ex, fr in [0.5,1)
    int E = ex - 1;
    float t = ldexpf(a, -E);                   // [1,2)
    int m3 = (int)rintf((t - 1.0f) * 8.0f);    // 0..8
    if (m3 == 8) { m3 = 0; E += 1; }
    if (E > 8) return (unsigned char)(s | 0x7E);
    return (unsigned char)(s | ((unsigned)(E + 7) << 3) | (unsigned)m3);
#endif
}

__device__ __forceinline__ float sigf(float x) { return 1.0f / (1.0f + __expf(-x)); }
__device__ __forceinline__ float tanhfast(float x) { return 1.0f - 2.0f / (1.0f + __expf(2.0f * x)); }

// lgkm-only barrier: LDS visibility without draining vmcnt.
// imm 0xC07F = vmcnt(63) expcnt(7) lgkmcnt(0).
__device__ __forceinline__ void barrier_lds_only() {
    __builtin_amdgcn_s_waitcnt(0xC07F);
    __builtin_amdgcn_s_barrier();
}

// =====================================================================
// K0: one-time weight conversion whh (fp32 [512][128], both dirs) -> fp8 e4m3
// scaled by 64 (keeps w ~ N(0,0.01) in e4m3's normal range).
// =====================================================================
__global__ __launch_bounds__(256) void k_wcvt(
    const float* __restrict__ wf, const float* __restrict__ wb,
    unsigned char* __restrict__ o)
{
    const int i = blockIdx.x * 256 + threadIdx.x;   // 0 .. 131071
    const float v = (i < 65536) ? wf[i] : wb[i - 65536];
    o[i] = f8enc(v * 64.0f);
}

// =====================================================================
// K1: input projection via bf16 MFMA (unchanged; writes G as [t][b][g] bf16).
// =====================================================================
__global__ __launch_bounds__(256) void k_inproj(
    const int* __restrict__ sent, const float* __restrict__ embed,
    const float* __restrict__ w_ih_f, const float* __restrict__ b_ih_f, const float* __restrict__ b_hh_f,
    const float* __restrict__ w_ih_b, const float* __restrict__ b_ih_b, const float* __restrict__ b_hh_b,
    unsigned short* __restrict__ G_f, unsigned short* __restrict__ G_b)
{
    __shared__ unsigned short Asm[128][136];
    __shared__ unsigned short Bsm[128][136];
    const int tid = threadIdx.x;
    const int dir = blockIdx.z;
    const float* w_ih = dir ? w_ih_b : w_ih_f;
    const float* bi   = dir ? b_ih_b : b_ih_f;
    const float* bh   = dir ? b_hh_b : b_hh_f;
    unsigned short* Gout = dir ? G_b : G_f;

    const int mt = blockIdx.x, nt = blockIdx.y;
    const int r0 = mt * 128, n0 = nt * 128;

    const int srow = tid >> 1;
    const int ch = (tid & 1) * 64;
    {
        const int rg = r0 + srow;
        const int tt = rg >> 6, bb = rg & 63;
        const int tok = sent[bb * Tn + tt];
        const float* ar = embed + (size_t)tok * En + ch;
        const float* br = w_ih + (size_t)(n0 + srow) * En + ch;
#pragma unroll
        for (int i = 0; i < 64; i += 4) {
            float4 v = *(const float4*)(ar + i);
            *(unsigned*)&Asm[srow][ch + i]     = (unsigned)f2bf(v.x) | ((unsigned)f2bf(v.y) << 16);
            *(unsigned*)&Asm[srow][ch + i + 2] = (unsigned)f2bf(v.z) | ((unsigned)f2bf(v.w) << 16);
            float4 u = *(const float4*)(br + i);
            *(unsigned*)&Bsm[srow][ch + i]     = (unsigned)f2bf(u.x) | ((unsigned)f2bf(u.y) << 16);
            *(unsigned*)&Bsm[srow][ch + i + 2] = (unsigned)f2bf(u.z) | ((unsigned)f2bf(u.w) << 16);
        }
    }
    __syncthreads();

    const int w = tid >> 6, lane = tid & 63;
    const int ln = lane & 15, lq = lane >> 4;
    const int nwb = w * 32;

    fl4 acc[8][2];
#pragma unroll
    for (int mi = 0; mi < 8; ++mi)
#pragma unroll
        for (int ni = 0; ni < 2; ++ni) acc[mi][ni] = (fl4){0.f, 0.f, 0.f, 0.f};

#pragma unroll
    for (int kt = 0; kt < 4; ++kt) {
        const int kc = kt * 32 + lq * 8;
        bh8 a[8], bf[2];
#pragma unroll
        for (int mi = 0; mi < 8; ++mi) a[mi] = *(const bh8*)&Asm[mi * 16 + ln][kc];
#pragma unroll
        for (int ni = 0; ni < 2; ++ni) bf[ni] = *(const bh8*)&Bsm[nwb + ni * 16 + ln][kc];
#pragma unroll
        for (int mi = 0; mi < 8; ++mi)
#pragma unroll
            for (int ni = 0; ni < 2; ++ni)
                acc[mi][ni] = __builtin_amdgcn_mfma_f32_16x16x32_bf16(a[mi], bf[ni], acc[mi][ni], 0, 0, 0);
    }

    float bias[2];
#pragma unroll
    for (int ni = 0; ni < 2; ++ni) {
        int n = n0 + nwb + ni * 16 + ln;
        bias[ni] = bi[n] + bh[n];
    }
#pragma unroll
    for (int mi = 0; mi < 8; ++mi)
#pragma unroll
        for (int ni = 0; ni < 2; ++ni) {
            const int n = n0 + nwb + ni * 16 + ln;
#pragma unroll
            for (int rg = 0; rg < 4; ++rg) {
                const int m = mi * 16 + lq * 4 + rg;
                const size_t r = (size_t)(r0 + m);
                Gout[(r << 9) + n] = f2bf(acc[mi][ni][rg] + bias[ni]);
            }
        }
}

// =====================================================================
// K2: LSTM recurrence on the MATRIX pipe with K=128 fp8 MFMA (the R12 fix).
// R11 post-mortem: f16 K=32 forces 128 MFMAs/WG/step (1/16 utilization) =
// ~620 cyc/SIMD/step of matrix pipe (matches measured MfmaUtil). fp8 K=128
// contracts the whole hidden dim per instruction: 32 MFMAs/WG/step
// (~276 cyc/SIMD), and the 4 per-gate MFMAs are now INDEPENDENT (no chain).
// W: fp8 e4m3 x64 (k_wcvt). h: fp8 x16 in LDS (global copy stays bf16).
// Descale 1/1024 before adding G. Unity block-scales (E8M0=127 bytes).
// Operand roles as in R9-R11: A = h broadcast rows, B = W (gate = column);
// lane (w,ln) owns j = w*16+ln, all 4 gates in a0..a3[0].
// G: 4-slot static register pipeline (prefetch dist 4), lgkm-only barrier.
// =====================================================================
__global__ __launch_bounds__(512, 2) void k_lstm(
    const unsigned char* __restrict__ whh8,
    const unsigned short* __restrict__ G_f, const unsigned short* __restrict__ G_b,
    unsigned short* __restrict__ h_f, unsigned short* __restrict__ h_b)
{
    const int tid = threadIdx.x;
    const int w = tid >> 6;
    const int lane = tid & 63;
    const int ln = lane & 15;
    const int quad = lane >> 4;
    const int b = blockIdx.x;           // batch (one per WG)
    const int dir = blockIdx.y;
    const unsigned short* Gd = dir ? G_b : G_f;
    unsigned short* ho = dir ? h_b : h_f;

    const int j = w * 16 + ln;          // this lane's h index (gate column)

    __shared__ __align__(16) unsigned char hls8[2][128];   // fp8 h (x16), double-buffered

    // ---- weights (B-frags): lane provides B[k=quad*32+i][n=ln] = W8[q*128+j][quad*32+i]
    const unsigned char* wb8 = whh8 + (size_t)dir * 65536;
    const i8v w0 = *(const i8v*)(wb8 + ((size_t)(0 * 128 + j) << 7) + quad * 32);
    const i8v w1 = *(const i8v*)(wb8 + ((size_t)(1 * 128 + j) << 7) + quad * 32);
    const i8v w2 = *(const i8v*)(wb8 + ((size_t)(2 * 128 + j) << 7) + quad * 32);
    const i8v w3 = *(const i8v*)(wb8 + ((size_t)(3 * 128 + j) << 7) + quad * 32);

    // zero both h buffers (2*128 fp8 = 64 dwords); fp8 0x00 == 0.0
    if (tid < 64) ((unsigned*)hls8)[tid] = 0u;
    float c = 0.0f;
    __syncthreads();

    // ---- G pipeline preload: slot u holds the 4 gate pre-acts of step u ----
    unsigned short gp[4][4];
#pragma unroll
    for (int u = 0; u < 4; ++u) {
        const int tt = dir ? (Tn - 1 - u) : u;
        const unsigned short* gpp = Gd + (((size_t)tt * Bn + b) << 9) + j;
#pragma unroll
        for (int q = 0; q < 4; ++q) gp[u][q] = gpp[q * 128];
    }

    const float ds = 0.0009765625f;     // 1/(64*16) descale

    for (int blk = 0; blk < Tn / 4; ++blk) {
#pragma unroll
        for (int u = 0; u < 4; ++u) {
            const int s = blk * 4 + u;
            const int t = dir ? (Tn - 1 - s) : s;
            const int p = u & 1;          // h buffer parity (blk*4 is even)

            // consume slot u (loaded at step s-4; vmcnt wait finds it done)
            const unsigned short ga0 = gp[u][0], ga1 = gp[u][1];
            const unsigned short ga2 = gp[u][2], ga3 = gp[u][3];

            // prefetch step s+4 into slot u (static index -> no copies)
            if (s + 4 < Tn) {
                const int tt = dir ? (Tn - 1 - (s + 4)) : (s + 4);
                const unsigned short* gpp = Gd + (((size_t)tt * Bn + b) << 9) + j;
#pragma unroll
                for (int q = 0; q < 4; ++q) gp[u][q] = gpp[q * 128];
            }

            // ---- A-frag: 32 fp8 of h, k = quad*32 .. +32 (broadcast across ln)
            i8v ha = *(const i8v*)&hls8[p][quad * 32];

            // ---- 4 INDEPENDENT K=128 fp8 MFMAs: aq = dot(h, W[q*128+j]) * 1024
            const fl4 z = (fl4){0.f, 0.f, 0.f, 0.f};
            fl4 a0 = __builtin_amdgcn_mfma_scale_f32_16x16x128_f8f6f4(
                         ha, w0, z, 0, 0, 0, 0x7F7F7F7F, 0, 0x7F7F7F7F);
            fl4 a1 = __builtin_amdgcn_mfma_scale_f32_16x16x128_f8f6f4(
                         ha, w1, z, 0, 0, 0, 0x7F7F7F7F, 0, 0x7F7F7F7F);
            fl4 a2 = __builtin_amdgcn_mfma_scale_f32_16x16x128_f8f6f4(
                         ha, w2, z, 0, 0, 0, 0x7F7F7F7F, 0, 0x7F7F7F7F);
            fl4 a3 = __builtin_amdgcn_mfma_scale_f32_16x16x128_f8f6f4(
                         ha, w3, z, 0, 0, 0, 0x7F7F7F7F, 0, 0x7F7F7F7F);

            // ---- activation: ONE h-element per lane (replicated across quads) ----
            float pi = a0[0] * ds + bf2f(ga0);
            float pf = a1[0] * ds + bf2f(ga1);
            float pg = a2[0] * ds + bf2f(ga2);
            float po = a3[0] * ds + bf2f(ga3);
            float iv = sigf(pi), fv = sigf(pf), gv = tanhfast(pg), ov = sigf(po);
            c = fv * c + iv * gv;
            float hn = ov * tanhfast(c);

            // ---- h writes (quad==0 lanes cover all 128 j): LDS fp8(x16) + global bf16
            if (quad == 0) {
                hls8[1 - p][j] = f8enc(hn * 16.0f);
                ho[(((size_t)t * Bn + b) << 7) + j] = f2bf(hn);
            }

            barrier_lds_only();
        }
    }
}

// =====================================================================
// K3: feats (unchanged).
// =====================================================================
__global__ __launch_bounds__(256) void k_feats(
    const unsigned short* __restrict__ h_f, const unsigned short* __restrict__ h_b,
    const float* __restrict__ w_out, const float* __restrict__ b_out,
    float* __restrict__ feats)
{
    __shared__ float wl[256][12];
    __shared__ float bl[12];
    const int tid = threadIdx.x;
#pragma unroll
    for (int s = 0; s < 9; ++s) wl[tid][s] = w_out[s * 256 + tid];
#pragma unroll
    for (int s = 9; s < 12; ++s) wl[tid][s] = 0.0f;
    if (tid < 12) bl[tid] = (tid < 9) ? b_out[tid] : 0.0f;
    __syncthreads();

    const int r = blockIdx.x * 256 + tid;
    const unsigned short* hfr = h_f + (size_t)r * 128;
    const unsigned short* hbr = h_b + (size_t)r * 128;
    float acc[12];
#pragma unroll
    for (int k = 0; k < 12; ++k) acc[k] = bl[k];

    for (int ch = 0; ch < 32; ++ch) {
        const unsigned short* src = (ch < 16) ? (hfr + ch * 8) : (hbr + (ch - 16) * 8);
        uint4 hv = *(const uint4*)src;
        unsigned int hw0 = hv.x, hw1 = hv.y, hw2 = hv.z, hw3 = hv.w;
        const int jb = ch * 8;
#pragma unroll
        for (int q = 0; q < 8; ++q) {
            unsigned int word = (q < 2) ? hw0 : ((q < 4) ? hw1 : ((q < 6) ? hw2 : hw3));
            unsigned short hs = (q & 1) ? (unsigned short)(word >> 16) : (unsigned short)(word & 0xffff);
            float hf = bf2f(hs);
            const float* wrp = &wl[jb + q][0];
            float4 w0 = *(const float4*)(wrp);
            float4 w1 = *(const float4*)(wrp + 4);
            float4 w2 = *(const float4*)(wrp + 8);
            acc[0] += hf * w0.x; acc[1] += hf * w0.y; acc[2] += hf * w0.z; acc[3] += hf * w0.w;
            acc[4] += hf * w1.x; acc[5] += hf * w1.y; acc[6] += hf * w1.z; acc[7] += hf * w1.w;
            acc[8] += hf * w2.x; acc[9] += hf * w2.y; acc[10] += hf * w2.z; acc[11] += hf * w2.w;
        }
    }
    float* fr = feats + (size_t)r * 9;
#pragma unroll
    for (int k = 0; k < 9; ++k) fr[k] = acc[k];
}

// =====================================================================
// K4: Viterbi (unchanged).
// =====================================================================
__global__ __launch_bounds__(64) void k_viterbi(
    const float* __restrict__ feats, const float* __restrict__ trans,
    float* __restrict__ out)
{
    __shared__ __align__(16) unsigned char bp[1024 * 16];
    __shared__ float fl[1024 * 9];
    __shared__ float dl[12];
    __shared__ unsigned char pt[1024];

    const int b = blockIdx.x, tid = threadIdx.x;

    for (int i = tid; i < 9216; i += 64) {
        int t = i / 9;
        int n = i - t * 9;
        fl[i] = feats[((size_t)t * 64 + b) * 9 + n];
    }

    float tr[9];
    float trs = -3.0e38f;
    if (tid < 9) {
#pragma unroll
        for (int p = 0; p < 9; ++p) tr[p] = trans[tid * 9 + p];
        trs = trans[8 * 9 + tid];
    }
    if (tid < 12) dl[tid] = (tid == 7) ? 0.0f : NEGV;
    __syncthreads();

    if (tid < 9) {
        for (int t = 0; t < 1024; ++t) {
            float4 d0 = *(const float4*)&dl[0];
            float4 d1 = *(const float4*)&dl[4];
            float d8 = dl[8];
            float dv0 = d0.x, dv1 = d0.y, dv2 = d0.z, dv3 = d0.w;
            float dv4 = d1.x, dv5 = d1.y, dv6 = d1.z, dv7 = d1.w;
            float m = dv0 + tr[0]; int am = 0;
            float v;
            v = dv1 + tr[1]; if (v > m) { m = v; am = 1; }
            v = dv2 + tr[2]; if (v > m) { m = v; am = 2; }
            v = dv3 + tr[3]; if (v > m) { m = v; am = 3; }
            v = dv4 + tr[4]; if (v > m) { m = v; am = 4; }
            v = dv5 + tr[5]; if (v > m) { m = v; am = 5; }
            v = dv6 + tr[6]; if (v > m) { m = v; am = 6; }
            v = dv7 + tr[7]; if (v > m) { m = v; am = 7; }
            v = d8  + tr[8]; if (v > m) { m = v; am = 8; }
            float nd = m + fl[t * 9 + tid];
            dl[tid] = nd;
            bp[t * 16 + tid] = (unsigned char)am;
        }
    }
    float tv = (tid < 9) ? (dl[tid] + trs) : -3.0e38f;
    int bi = tid;
#pragma unroll
    for (int off = 8; off >= 1; off >>= 1) {
        float ov = __shfl_down(tv, off, 64);
        int oi = __shfl_down(bi, off, 64);
        if (ov > tv || (ov == tv && oi < bi)) { tv = ov; bi = oi; }
    }
    int best = __shfl(bi, 0, 64);
    if (tid == 0) out[b] = tv;

    if (tid == 0) {
        int tag = best;
        for (int t0 = 1023; t0 >= 0; t0 -= 8) {
            uint4 rows[8];
#pragma unroll
            for (int i = 0; i < 8; ++i) rows[i] = *(const uint4*)&bp[(t0 - i) * 16];
#pragma unroll
            for (int i = 0; i < 8; ++i) {
                pt[t0 - i] = (unsigned char)tag;
                uint4 rw = rows[i];
                unsigned int sel = (unsigned int)tag >> 2;
                unsigned int word = (sel == 0) ? rw.x : ((sel == 1) ? rw.y : rw.z);
                tag = (int)((word >> ((tag & 3) * 8)) & 0xffu);
            }
        }
    }
    for (int i = tid; i < 1024; i += 64) {
        out[64 + b * 1024 + i] = (float)pt[i];
    }
}

// =====================================================================
extern "C" void kernel_launch(void* const* d_in, const int* in_sizes, int n_in,
                              void* d_out, int out_size, void* d_ws, size_t ws_size,
                              hipStream_t stream) {
    const int*   sent   = (const int*)d_in[0];
    const float* embed  = (const float*)d_in[1];
    const float* w_ih_f = (const float*)d_in[2];
    const float* w_hh_f = (const float*)d_in[3];
    const float* b_ih_f = (const float*)d_in[4];
    const float* b_hh_f = (const float*)d_in[5];
    const float* w_ih_b = (const float*)d_in[6];
    const float* w_hh_b = (const float*)d_in[7];
    const float* b_ih_b = (const float*)d_in[8];
    const float* b_hh_b = (const float*)d_in[9];
    const float* w_out  = (const float*)d_in[10];
    const float* b_out  = (const float*)d_in[11];
    const float* trans  = (const float*)d_in[12];
    float* out = (float*)d_out;

    unsigned short* G_f = (unsigned short*)d_ws;
    unsigned short* G_b = G_f + (size_t)Tn * Bn * G4;
    unsigned short* h_f = G_b + (size_t)Tn * Bn * G4;
    unsigned short* h_b = h_f + (size_t)Tn * Bn * 128;
    float* feats = (float*)(h_b + (size_t)Tn * Bn * 128);
    unsigned char* whh8 = (unsigned char*)(feats + (size_t)Tn * Bn * 9);

    k_wcvt<<<512, 256, 0, stream>>>(w_hh_f, w_hh_b, whh8);
    k_inproj<<<dim3(512, 4, 2), 256, 0, stream>>>(sent, embed,
        w_ih_f, b_ih_f, b_hh_f, w_ih_b, b_ih_b, b_hh_b, G_f, G_b);
    k_lstm<<<dim3(64, 2), 512, 0, stream>>>(whh8, G_f, G_b, h_f, h_b);
    k_feats<<<256, 256, 0, stream>>>(h_f, h_b, w_out, b_out, feats);
    k_viterbi<<<64, 64, 0, stream>>>(feats, trans, out);
}